// Round 5
// baseline (210.886 us; speedup 1.0000x reference)
//
#include <hip/hip_runtime.h>
#include <math.h>

#define N_TOK 4096
#define CDIM  1024
#define NH    16
#define HD    64

// scores: |q̂γ · k̂γ√D| <= 8 (γ=1). Static softmax max = 8, folded into
// K scale (8*log2e) + MFMA C-init bias (-8*log2e). P = exp2(S) directly.
#define KSCALE 11.5416469f   // 8 * log2(e)
#define SBIAS (-11.5416469f)

typedef __attribute__((ext_vector_type(8)))  __bf16 bf16x8;
typedef __attribute__((ext_vector_type(4)))  float  f32x4;
typedef __attribute__((ext_vector_type(16))) float  f32x16;
typedef __attribute__((ext_vector_type(4)))  unsigned int u32x4;

__device__ __forceinline__ unsigned short f2bf(float f) {
  unsigned int u = __builtin_bit_cast(unsigned int, f);
  u += 0x7FFFu + ((u >> 16) & 1u);            // RTNE
  return (unsigned short)(u >> 16);
}

__device__ __forceinline__ unsigned int cvt_pk_bf16(float lo, float hi) {
  unsigned int w;
  asm("v_cvt_pk_bf16_f32 %0, %1, %2" : "=v"(w) : "v"(lo), "v"(hi));
  return w;
}

__device__ __forceinline__ void gload_lds16(const void* g, void* lds) {
  __builtin_amdgcn_global_load_lds(
      (const __attribute__((address_space(1))) unsigned int*)g,
      (__attribute__((address_space(3))) unsigned int*)lds, 16, 0, 0);
}

// ---------------------------------------------------------------- pack fp32->bf16
__global__ __launch_bounds__(256) void pack_bf16_kernel(
    const float* __restrict__ x, const float* __restrict__ w1,
    const float* __restrict__ w2, unsigned short* __restrict__ xb,
    unsigned short* __restrict__ w1b, unsigned short* __restrict__ w2b) {
  const size_t X4 = (size_t)N_TOK * CDIM / 4;
  const size_t W14 = (size_t)3 * CDIM * CDIM / 4;
  const size_t W24 = (size_t)CDIM * CDIM / 4;
  size_t i = (size_t)blockIdx.x * blockDim.x + threadIdx.x;
  const float* src; unsigned short* dst; size_t off;
  if (i < X4)              { src = x;  dst = xb;  off = i; }
  else if (i < X4 + W14)   { src = w1; dst = w1b; off = i - X4; }
  else if (i < X4 + W14 + W24) { src = w2; dst = w2b; off = i - X4 - W14; }
  else return;
  float4 v = reinterpret_cast<const float4*>(src)[off];
  ushort4 u;
  u.x = f2bf(v.x); u.y = f2bf(v.y); u.z = f2bf(v.z); u.w = f2bf(v.w);
  reinterpret_cast<ushort4*>(dst)[off] = u;
}

// ---------------------------------------------------------------- bf16 GEMM, C = A * B^T + bias
__global__ __launch_bounds__(256, 2) void gemm_bt_kernel(
    const unsigned short* __restrict__ A, const unsigned short* __restrict__ B,
    const float* __restrict__ bias, float* __restrict__ C,
    int M, int Ncols, int K) {
  __shared__ alignas(16) char As[128 * 128];
  __shared__ alignas(16) char Bs[128 * 128];
  const int t = threadIdx.x;
  const int lane = t & 63, wave = t >> 6;
  const int wr = wave >> 1, wc = wave & 1;
  const int lrow = lane & 15, lk = lane >> 4;
  const int row0 = blockIdx.x * 128, col0 = blockIdx.y * 128;
  const f32x4 fzero = {0.f, 0.f, 0.f, 0.f};

  f32x4 acc[4][4];
#pragma unroll
  for (int m = 0; m < 4; ++m)
#pragma unroll
    for (int n = 0; n < 4; ++n) acc[m][n] = fzero;

  const int p_row = (t * 16) >> 7;
  const int p_cb  = (t * 16) & 127;

  for (int kt = 0; kt < K; kt += 64) {
    __syncthreads();
#pragma unroll
    for (int c = 0; c < 4; ++c) {
      int row = c * 32 + p_row;
      int kb = p_cb ^ ((row & 7) << 4);
      const char* gA = (const char*)A + ((size_t)(row0 + row) * K + kt) * 2 + kb;
      const char* gB = (const char*)B + ((size_t)(col0 + row) * K + kt) * 2 + kb;
      gload_lds16(gA, As + c * 4096 + wave * 1024);
      gload_lds16(gB, Bs + c * 4096 + wave * 1024);
    }
    __syncthreads();
#pragma unroll
    for (int kk = 0; kk < 2; ++kk) {
      bf16x8 a[4], b[4];
#pragma unroll
      for (int m = 0; m < 4; ++m) {
        int r = wr * 64 + m * 16 + lrow;
        a[m] = *reinterpret_cast<const bf16x8*>(
            As + r * 128 + ((kk * 64 + lk * 16) ^ ((r & 7) << 4)));
      }
#pragma unroll
      for (int n = 0; n < 4; ++n) {
        int r = wc * 64 + n * 16 + lrow;
        b[n] = *reinterpret_cast<const bf16x8*>(
            Bs + r * 128 + ((kk * 64 + lk * 16) ^ ((r & 7) << 4)));
      }
#pragma unroll
      for (int m = 0; m < 4; ++m)
#pragma unroll
        for (int n = 0; n < 4; ++n)
          acc[m][n] = __builtin_amdgcn_mfma_f32_16x16x32_bf16(a[m], b[n], acc[m][n], 0, 0, 0);
    }
  }

#pragma unroll
  for (int m = 0; m < 4; ++m) {
    int row = row0 + wr * 64 + m * 16 + lk * 4;
#pragma unroll
    for (int n = 0; n < 4; ++n) {
      int col = col0 + wc * 64 + n * 16 + lrow;
      float bv = bias[col];
#pragma unroll
      for (int j = 0; j < 4; ++j)
        C[(size_t)(row + j) * Ncols + col] = acc[m][n][j] + bv;
    }
  }
}

// ---------------------------------------------------------------- per-head RMS norm + layout
// Q: [H][N][D] bf16 = q̂*gamma
// K: [H][N][D] bf16 = k̂*gamma * 8*log2e
// V: [H][D][N'] bf16, N' = key index with bits2<->3 swapped (PV slot->key map)
__global__ __launch_bounds__(256) void rmsnorm_kernel(
    const float* __restrict__ qkv, const float* __restrict__ qg,
    const float* __restrict__ kg, unsigned short* __restrict__ Qn,
    unsigned short* __restrict__ Kn, unsigned short* __restrict__ Vt) {
  const int t = threadIdx.x, d = t & 63, w = t >> 6;
  const int h = blockIdx.y;
  const int n0 = blockIdx.x * 64 + w * 16;
  const float gq = qg[h * HD + d], gk = kg[h * HD + d];
  for (int i = 0; i < 16; ++i) {
    const int n = n0 + i;
    const float* base = qkv + (size_t)n * 3 * CDIM + h * HD + d;
    float qv = base[0], kv = base[CDIM], vv = base[2 * CDIM];
    float sq = qv * qv, sk = kv * kv;
#pragma unroll
    for (int off = 1; off < 64; off <<= 1) {
      sq += __shfl_xor(sq, off);
      sk += __shfl_xor(sk, off);
    }
    float rq = rsqrtf(fmaxf(sq, 1e-24f));
    float rk = rsqrtf(fmaxf(sk, 1e-24f));
    size_t qoff = ((size_t)h * N_TOK + n) * HD + d;
    Qn[qoff] = f2bf(qv * rq * gq);
    Kn[qoff] = f2bf(kv * rk * gk * KSCALE);
    int np = (n & ~12) | ((n & 4) << 1) | ((n & 8) >> 1);  // swap bits 2,3
    Vt[(size_t)(h * HD + d) * N_TOK + np] = f2bf(vv);
  }
}

// ---------------------------------------------------------------- flash attention v5 (split-KV, sequenced halves)
// blockIdx.z = KV half. Per 64-key tile: {QK(s) -> exp/pack -> PV} twice,
// so only one f32x16 score block is live; persistent SB C-operand kills
// the per-tile accumulator-init movs. Target 4 waves/SIMD.
__global__ __launch_bounds__(256, 4) void flash_kernel(
    const unsigned short* __restrict__ Qn, const unsigned short* __restrict__ Kn,
    const unsigned short* __restrict__ Vt, float* __restrict__ Op,
    float* __restrict__ Lp) {
  __shared__ alignas(16) char Ks[2][64 * 128];
  __shared__ alignas(16) char Vs[2][64 * 128];
  const int t = threadIdx.x, lane = t & 63, wave = t >> 6;
  const int q = lane & 31, hi = lane >> 5;
  const int h = blockIdx.y;
  const int half = blockIdx.z;
  const int q0 = blockIdx.x * 128 + wave * 32;
  const int kv0 = half << 11;

  bf16x8 bq[4];
#pragma unroll
  for (int c = 0; c < 4; ++c)
    bq[c] = *reinterpret_cast<const bf16x8*>(
        Qn + ((size_t)h * N_TOK + q0 + q) * HD + c * 16 + hi * 8);

  f32x16 SB;
#pragma unroll
  for (int r = 0; r < 16; ++r) SB[r] = SBIAS;

  f32x16 ot0, ot1;
#pragma unroll
  for (int r = 0; r < 16; ++r) { ot0[r] = 0.f; ot1[r] = 0.f; }
  float l = 0.f;

  const int p_row = (t * 16) >> 7;
  const int p_cb  = (t * 16) & 127;

  auto stage = [&](int b, int kvoff) {
#pragma unroll
    for (int c = 0; c < 2; ++c) {
      int row = c * 32 + p_row;
      int cb = p_cb ^ ((row & 7) << 4);
      const char* gK = (const char*)Kn + ((size_t)h * N_TOK + kvoff + row) * 128 + cb;
      const char* gV = (const char*)Vt + ((size_t)(h * HD + row) * N_TOK + kvoff) * 2 + cb;
      gload_lds16(gK, Ks[b] + c * 4096 + wave * 1024);
      gload_lds16(gV, Vs[b] + c * 4096 + wave * 1024);
    }
  };

  stage(0, kv0);
  int buf = 0;

  for (int kv = kv0; kv < kv0 + 2048; kv += 64) {
    __syncthreads();
    if (kv + 64 < kv0 + 2048) stage(buf ^ 1, kv + 64);

    const char* Kb = Ks[buf];
    const char* Vb = Vs[buf];

#pragma unroll
    for (int hblk = 0; hblk < 2; ++hblk) {      // keys hblk*32 .. hblk*32+31
      const int krow = hblk * 32 + q;
      f32x16 s;
      __builtin_amdgcn_s_setprio(1);
#pragma unroll
      for (int c = 0; c < 4; ++c) {
        bf16x8 kf = *reinterpret_cast<const bf16x8*>(
            Kb + krow * 128 + ((c * 32 + hi * 16) ^ ((krow & 7) << 4)));
        s = __builtin_amdgcn_mfma_f32_32x32x16_bf16(kf, bq[c], (c == 0) ? SB : s,
                                                    0, 0, 0);
      }
      __builtin_amdgcn_s_setprio(0);

      float ps = 0.f;
#pragma unroll
      for (int r = 0; r < 16; ++r) {
        float p = exp2f(s[r]);
        s[r] = p; ps += p;
      }
      l += ps;

      unsigned int W[8];
#pragma unroll
      for (int i = 0; i < 8; ++i)
        W[i] = cvt_pk_bf16(s[2 * i], s[2 * i + 1]);

      __builtin_amdgcn_s_setprio(1);
#pragma unroll
      for (int ktl = 0; ktl < 2; ++ktl) {       // key-subtiles of 16
        const int kt = hblk * 2 + ktl;
        u32x4 pw;
#pragma unroll
        for (int i = 0; i < 4; ++i) pw[i] = W[ktl * 4 + i];
        bf16x8 pfrag = __builtin_bit_cast(bf16x8, pw);
        {
          int dr = q;
          bf16x8 vf = *reinterpret_cast<const bf16x8*>(
              Vb + dr * 128 + ((kt * 32 + hi * 16) ^ ((dr & 7) << 4)));
          ot0 = __builtin_amdgcn_mfma_f32_32x32x16_bf16(vf, pfrag, ot0, 0, 0, 0);
        }
        {
          int dr = 32 + q;
          bf16x8 vf = *reinterpret_cast<const bf16x8*>(
              Vb + dr * 128 + ((kt * 32 + hi * 16) ^ ((dr & 7) << 4)));
          ot1 = __builtin_amdgcn_mfma_f32_32x32x16_bf16(vf, pfrag, ot1, 0, 0, 0);
        }
      }
      __builtin_amdgcn_s_setprio(0);
    }
    buf ^= 1;
  }

  // un-normalized partial out (fp32) + denominator partial
  float* ob = Op + ((size_t)half * N_TOK + q0 + q) * CDIM + h * HD;
#pragma unroll
  for (int g = 0; g < 4; ++g) {
    float4 v0 = {ot0[4 * g + 0], ot0[4 * g + 1], ot0[4 * g + 2], ot0[4 * g + 3]};
    float4 v1 = {ot1[4 * g + 0], ot1[4 * g + 1], ot1[4 * g + 2], ot1[4 * g + 3]};
    *reinterpret_cast<float4*>(ob + g * 8 + hi * 4) = v0;
    *reinterpret_cast<float4*>(ob + 32 + g * 8 + hi * 4) = v1;
  }
  l += __shfl_xor(l, 32);
  if (hi == 0)
    Lp[((size_t)half * NH + h) * N_TOK + q0 + q] = l;
}

// ---------------------------------------------------------------- combine halves -> bf16 Hb
__global__ __launch_bounds__(256) void combine_kernel(
    const float* __restrict__ Op, const float* __restrict__ Lp,
    unsigned short* __restrict__ Hb) {
  int i = blockIdx.x * 256 + threadIdx.x;          // float4 index, N*C/4 total
  int c = (i & (CDIM / 4 - 1)) * 4;
  int n = i >> 8;
  int h = c >> 6;
  float l0 = Lp[(size_t)h * N_TOK + n];
  float l1 = Lp[((size_t)NH + h) * N_TOK + n];
  float rl = 1.0f / (l0 + l1);
  float4 a = reinterpret_cast<const float4*>(Op)[i];
  float4 b = reinterpret_cast<const float4*>(Op + (size_t)N_TOK * CDIM)[i];
  ushort4 u;
  u.x = f2bf((a.x + b.x) * rl);
  u.y = f2bf((a.y + b.y) * rl);
  u.z = f2bf((a.z + b.z) * rl);
  u.w = f2bf((a.w + b.w) * rl);
  reinterpret_cast<ushort4*>(Hb)[i] = u;
}

// ---------------------------------------------------------------- launch
extern "C" void kernel_launch(void* const* d_in, const int* in_sizes, int n_in,
                              void* d_out, int out_size, void* d_ws, size_t ws_size,
                              hipStream_t stream) {
  const float* x    = (const float*)d_in[0];
  const float* Wqkv = (const float*)d_in[1];
  const float* bqkv = (const float*)d_in[2];
  const float* qg   = (const float*)d_in[3];
  const float* kg   = (const float*)d_in[4];
  const float* Wout = (const float*)d_in[5];
  const float* bout = (const float*)d_in[6];
  float* out = (float*)d_out;

  char* ws = (char*)d_ws;
  unsigned short* xb  = (unsigned short*)(ws);
  unsigned short* w1b = (unsigned short*)(ws + ((size_t)8  << 20));
  unsigned short* w2b = (unsigned short*)(ws + ((size_t)14 << 20));
  float*          qkv = (float*)         (ws + ((size_t)16 << 20));  // dead after rmsnorm
  float*          Op  = (float*)         (ws + ((size_t)16 << 20));  // reuses qkv region (32MB)
  float*          Lp  = (float*)         (ws + ((size_t)48 << 20));  // 0.5MB
  unsigned short* Qn  = (unsigned short*)(ws + ((size_t)64 << 20));
  unsigned short* Kn  = (unsigned short*)(ws + ((size_t)72 << 20));
  unsigned short* Vt  = (unsigned short*)(ws + ((size_t)80 << 20));
  unsigned short* Hb  = (unsigned short*)(ws + ((size_t)88 << 20));

  pack_bf16_kernel<<<8192, 256, 0, stream>>>(x, Wqkv, Wout, xb, w1b, w2b);
  gemm_bt_kernel<<<dim3(32, 24), 256, 0, stream>>>(xb, w1b, bqkv, qkv,
                                                   N_TOK, 3 * CDIM, CDIM);
  rmsnorm_kernel<<<dim3(64, 16), 256, 0, stream>>>(qkv, qg, kg, Qn, Kn, Vt);
  flash_kernel<<<dim3(32, 16, 2), 256, 0, stream>>>(Qn, Kn, Vt, Op, Lp);
  combine_kernel<<<4096, 256, 0, stream>>>(Op, Lp, Hb);
  gemm_bt_kernel<<<dim3(32, 8), 256, 0, stream>>>(Hb, w2b, bout, out,
                                                  N_TOK, CDIM, CDIM);
}

// Round 6
// 180.186 us; speedup vs baseline: 1.1704x; 1.1704x over previous
//
#include <hip/hip_runtime.h>
#include <math.h>

#define N_TOK 4096
#define CDIM  1024
#define NH    16
#define HD    64

// scores: |q̂γ · k̂γ√D| <= 8 (γ=1), folded to log2 domain via K scale.
// No max subtraction needed: exp2(s) <= 2^11.55 = 2979, sums fit fp32 easily,
// and any constant bias cancels in O/l.
#define KSCALE 11.5416469f   // 8 * log2(e)

typedef __attribute__((ext_vector_type(8)))  __bf16 bf16x8;
typedef __attribute__((ext_vector_type(4)))  float  f32x4;
typedef __attribute__((ext_vector_type(16))) float  f32x16;
typedef __attribute__((ext_vector_type(4)))  unsigned int u32x4;

__device__ __forceinline__ unsigned short f2bf(float f) {
  unsigned int u = __builtin_bit_cast(unsigned int, f);
  u += 0x7FFFu + ((u >> 16) & 1u);            // RTNE
  return (unsigned short)(u >> 16);
}

__device__ __forceinline__ unsigned int cvt_pk_bf16(float lo, float hi) {
  unsigned int w;
  asm("v_cvt_pk_bf16_f32 %0, %1, %2" : "=v"(w) : "v"(lo), "v"(hi));
  return w;
}

// bare v_exp_f32 — inputs are in [-12, 12], no denormal handling needed
__device__ __forceinline__ float fexp2(float x) {
#if __has_builtin(__builtin_amdgcn_exp2f)
  return __builtin_amdgcn_exp2f(x);
#else
  return exp2f(x);
#endif
}

__device__ __forceinline__ void gload_lds16(const void* g, void* lds) {
  __builtin_amdgcn_global_load_lds(
      (const __attribute__((address_space(1))) unsigned int*)g,
      (__attribute__((address_space(3))) unsigned int*)lds, 16, 0, 0);
}

// ---------------------------------------------------------------- pack fp32->bf16
__global__ __launch_bounds__(256) void pack_bf16_kernel(
    const float* __restrict__ x, const float* __restrict__ w1,
    const float* __restrict__ w2, unsigned short* __restrict__ xb,
    unsigned short* __restrict__ w1b, unsigned short* __restrict__ w2b) {
  const size_t X4 = (size_t)N_TOK * CDIM / 4;
  const size_t W14 = (size_t)3 * CDIM * CDIM / 4;
  const size_t W24 = (size_t)CDIM * CDIM / 4;
  size_t i = (size_t)blockIdx.x * blockDim.x + threadIdx.x;
  const float* src; unsigned short* dst; size_t off;
  if (i < X4)              { src = x;  dst = xb;  off = i; }
  else if (i < X4 + W14)   { src = w1; dst = w1b; off = i - X4; }
  else if (i < X4 + W14 + W24) { src = w2; dst = w2b; off = i - X4 - W14; }
  else return;
  float4 v = reinterpret_cast<const float4*>(src)[off];
  ushort4 u;
  u.x = f2bf(v.x); u.y = f2bf(v.y); u.z = f2bf(v.z); u.w = f2bf(v.w);
  reinterpret_cast<ushort4*>(dst)[off] = u;
}

// ---------------------------------------------------------------- bf16 GEMM, C = A * B^T + bias
__global__ __launch_bounds__(256, 2) void gemm_bt_kernel(
    const unsigned short* __restrict__ A, const unsigned short* __restrict__ B,
    const float* __restrict__ bias, float* __restrict__ C,
    int M, int Ncols, int K) {
  __shared__ alignas(16) char As[128 * 128];
  __shared__ alignas(16) char Bs[128 * 128];
  const int t = threadIdx.x;
  const int lane = t & 63, wave = t >> 6;
  const int wr = wave >> 1, wc = wave & 1;
  const int lrow = lane & 15, lk = lane >> 4;
  const int row0 = blockIdx.x * 128, col0 = blockIdx.y * 128;
  const f32x4 fzero = {0.f, 0.f, 0.f, 0.f};

  f32x4 acc[4][4];
#pragma unroll
  for (int m = 0; m < 4; ++m)
#pragma unroll
    for (int n = 0; n < 4; ++n) acc[m][n] = fzero;

  const int p_row = (t * 16) >> 7;
  const int p_cb  = (t * 16) & 127;

  for (int kt = 0; kt < K; kt += 64) {
    __syncthreads();
#pragma unroll
    for (int c = 0; c < 4; ++c) {
      int row = c * 32 + p_row;
      int kb = p_cb ^ ((row & 7) << 4);
      const char* gA = (const char*)A + ((size_t)(row0 + row) * K + kt) * 2 + kb;
      const char* gB = (const char*)B + ((size_t)(col0 + row) * K + kt) * 2 + kb;
      gload_lds16(gA, As + c * 4096 + wave * 1024);
      gload_lds16(gB, Bs + c * 4096 + wave * 1024);
    }
    __syncthreads();
#pragma unroll
    for (int kk = 0; kk < 2; ++kk) {
      bf16x8 a[4], b[4];
#pragma unroll
      for (int m = 0; m < 4; ++m) {
        int r = wr * 64 + m * 16 + lrow;
        a[m] = *reinterpret_cast<const bf16x8*>(
            As + r * 128 + ((kk * 64 + lk * 16) ^ ((r & 7) << 4)));
      }
#pragma unroll
      for (int n = 0; n < 4; ++n) {
        int r = wc * 64 + n * 16 + lrow;
        b[n] = *reinterpret_cast<const bf16x8*>(
            Bs + r * 128 + ((kk * 64 + lk * 16) ^ ((r & 7) << 4)));
      }
#pragma unroll
      for (int m = 0; m < 4; ++m)
#pragma unroll
        for (int n = 0; n < 4; ++n)
          acc[m][n] = __builtin_amdgcn_mfma_f32_16x16x32_bf16(a[m], b[n], acc[m][n], 0, 0, 0);
    }
  }

#pragma unroll
  for (int m = 0; m < 4; ++m) {
    int row = row0 + wr * 64 + m * 16 + lk * 4;
#pragma unroll
    for (int n = 0; n < 4; ++n) {
      int col = col0 + wc * 64 + n * 16 + lrow;
      float bv = bias[col];
#pragma unroll
      for (int j = 0; j < 4; ++j)
        C[(size_t)(row + j) * Ncols + col] = acc[m][n][j] + bv;
    }
  }
}

// ---------------------------------------------------------------- per-head RMS norm + layout
// Q: [H][N][D] bf16 = q̂*gamma
// K: [H][N][D] bf16 = k̂*gamma * 8*log2e
// V: [H][D][N'] bf16, N' = key index with bits2<->3 swapped (PV slot->key map)
__global__ __launch_bounds__(256) void rmsnorm_kernel(
    const float* __restrict__ qkv, const float* __restrict__ qg,
    const float* __restrict__ kg, unsigned short* __restrict__ Qn,
    unsigned short* __restrict__ Kn, unsigned short* __restrict__ Vt) {
  const int t = threadIdx.x, d = t & 63, w = t >> 6;
  const int h = blockIdx.y;
  const int n0 = blockIdx.x * 64 + w * 16;
  const float gq = qg[h * HD + d], gk = kg[h * HD + d];
  for (int i = 0; i < 16; ++i) {
    const int n = n0 + i;
    const float* base = qkv + (size_t)n * 3 * CDIM + h * HD + d;
    float qv = base[0], kv = base[CDIM], vv = base[2 * CDIM];
    float sq = qv * qv, sk = kv * kv;
#pragma unroll
    for (int off = 1; off < 64; off <<= 1) {
      sq += __shfl_xor(sq, off);
      sk += __shfl_xor(sk, off);
    }
    float rq = rsqrtf(fmaxf(sq, 1e-24f));
    float rk = rsqrtf(fmaxf(sk, 1e-24f));
    size_t qoff = ((size_t)h * N_TOK + n) * HD + d;
    Qn[qoff] = f2bf(qv * rq * gq);
    Kn[qoff] = f2bf(kv * rk * gk * KSCALE);
    int np = (n & ~12) | ((n & 4) << 1) | ((n & 8) >> 1);  // swap bits 2,3
    Vt[(size_t)(h * HD + d) * N_TOK + np] = f2bf(vv);
  }
}

// ---------------------------------------------------------------- flash attention v6
// split-KV (blockIdx.z), sequenced 32-key halves, bare v_exp_f32 softmax,
// hoisted lane-invariant LDS offsets + pointer-increment staging.
__global__ __launch_bounds__(256, 4) void flash_kernel(
    const unsigned short* __restrict__ Qn, const unsigned short* __restrict__ Kn,
    const unsigned short* __restrict__ Vt, float* __restrict__ Op,
    float* __restrict__ Lp) {
  __shared__ alignas(16) char Ks[2][64 * 128];
  __shared__ alignas(16) char Vs[2][64 * 128];
  const int t = threadIdx.x, lane = t & 63, wave = t >> 6;
  const int q = lane & 31, hi = lane >> 5;
  const int h = blockIdx.y;
  const int half = blockIdx.z;
  const int q0 = blockIdx.x * 128 + wave * 32;
  const int kv0 = half << 11;

  bf16x8 bq[4];
#pragma unroll
  for (int c = 0; c < 4; ++c)
    bq[c] = *reinterpret_cast<const bf16x8*>(
        Qn + ((size_t)h * N_TOK + q0 + q) * HD + c * 16 + hi * 8);

  f32x16 ot0, ot1;
#pragma unroll
  for (int r = 0; r < 16; ++r) { ot0[r] = 0.f; ot1[r] = 0.f; }
  float l = 0.f;

  // loop-invariant swizzled LDS read offsets (lane constants)
  int koff[4], voff[4];
#pragma unroll
  for (int c = 0; c < 4; ++c)
    koff[c] = q * 128 + ((c * 32 + hi * 16) ^ ((q & 7) << 4));
#pragma unroll
  for (int kt = 0; kt < 4; ++kt)
    voff[kt] = q * 128 + ((kt * 32 + hi * 16) ^ ((q & 7) << 4));

  // persistent staging pointers, advanced per tile
  const int p_row = (t * 16) >> 7;
  const int p_cb  = (t * 16) & 127;
  const int scb   = p_cb ^ ((p_row & 7) << 4);
  const char* gK0 = (const char*)Kn + ((size_t)h * N_TOK + kv0 + p_row) * 128 + scb;
  const char* gK1 = gK0 + 32 * 128;
  const char* gV0 = (const char*)Vt + ((size_t)(h * HD + p_row) * N_TOK + kv0) * 2 + scb;
  const char* gV1 = gV0 + (size_t)32 * N_TOK * 2;

  auto stage = [&](int b) {
    char* dK = Ks[b] + wave * 1024;
    char* dV = Vs[b] + wave * 1024;
    gload_lds16(gK0, dK);
    gload_lds16(gK1, dK + 4096);
    gload_lds16(gV0, dV);
    gload_lds16(gV1, dV + 4096);
    gK0 += 8192; gK1 += 8192; gV0 += 128; gV1 += 128;
  };

  stage(0);
  int buf = 0;

  for (int kv = kv0; kv < kv0 + 2048; kv += 64) {
    __syncthreads();
    if (kv + 64 < kv0 + 2048) stage(buf ^ 1);

    const char* Kb = Ks[buf];
    const char* Vb = Vs[buf];

#pragma unroll
    for (int hblk = 0; hblk < 2; ++hblk) {      // keys hblk*32 .. hblk*32+31
      f32x16 s;
#pragma unroll
      for (int r = 0; r < 16; ++r) s[r] = 0.f;
      __builtin_amdgcn_s_setprio(1);
#pragma unroll
      for (int c = 0; c < 4; ++c) {
        bf16x8 kf = *reinterpret_cast<const bf16x8*>(Kb + koff[c] + hblk * 4096);
        s = __builtin_amdgcn_mfma_f32_32x32x16_bf16(kf, bq[c], s, 0, 0, 0);
      }
      __builtin_amdgcn_s_setprio(0);

      float ps = 0.f;
      unsigned int W[8];
#pragma unroll
      for (int i = 0; i < 8; ++i) {
        float p0 = fexp2(s[2 * i]);
        float p1 = fexp2(s[2 * i + 1]);
        W[i] = cvt_pk_bf16(p0, p1);
        ps += p0 + p1;
      }
      l += ps;

      __builtin_amdgcn_s_setprio(1);
#pragma unroll
      for (int ktl = 0; ktl < 2; ++ktl) {       // key-subtiles of 16
        const int kt = hblk * 2 + ktl;
        u32x4 pw;
#pragma unroll
        for (int i = 0; i < 4; ++i) pw[i] = W[ktl * 4 + i];
        bf16x8 pfrag = __builtin_bit_cast(bf16x8, pw);
        bf16x8 vf0 = *reinterpret_cast<const bf16x8*>(Vb + voff[kt]);
        ot0 = __builtin_amdgcn_mfma_f32_32x32x16_bf16(vf0, pfrag, ot0, 0, 0, 0);
        bf16x8 vf1 = *reinterpret_cast<const bf16x8*>(Vb + voff[kt] + 4096);
        ot1 = __builtin_amdgcn_mfma_f32_32x32x16_bf16(vf1, pfrag, ot1, 0, 0, 0);
      }
      __builtin_amdgcn_s_setprio(0);
    }
    buf ^= 1;
  }

  // un-normalized partial out (fp32) + denominator partial
  float* ob = Op + ((size_t)half * N_TOK + q0 + q) * CDIM + h * HD;
#pragma unroll
  for (int g = 0; g < 4; ++g) {
    float4 v0 = {ot0[4 * g + 0], ot0[4 * g + 1], ot0[4 * g + 2], ot0[4 * g + 3]};
    float4 v1 = {ot1[4 * g + 0], ot1[4 * g + 1], ot1[4 * g + 2], ot1[4 * g + 3]};
    *reinterpret_cast<float4*>(ob + g * 8 + hi * 4) = v0;
    *reinterpret_cast<float4*>(ob + 32 + g * 8 + hi * 4) = v1;
  }
  l += __shfl_xor(l, 32);
  if (hi == 0)
    Lp[((size_t)half * NH + h) * N_TOK + q0 + q] = l;
}

// ---------------------------------------------------------------- combine halves -> bf16 Hb
__global__ __launch_bounds__(256) void combine_kernel(
    const float* __restrict__ Op, const float* __restrict__ Lp,
    unsigned short* __restrict__ Hb) {
  int i = blockIdx.x * 256 + threadIdx.x;          // float4 index, N*C/4 total
  int c = (i & (CDIM / 4 - 1)) * 4;
  int n = i >> 8;
  int h = c >> 6;
  float l0 = Lp[(size_t)h * N_TOK + n];
  float l1 = Lp[((size_t)NH + h) * N_TOK + n];
  float rl = 1.0f / (l0 + l1);
  float4 a = reinterpret_cast<const float4*>(Op)[i];
  float4 b = reinterpret_cast<const float4*>(Op + (size_t)N_TOK * CDIM)[i];
  ushort4 u;
  u.x = f2bf((a.x + b.x) * rl);
  u.y = f2bf((a.y + b.y) * rl);
  u.z = f2bf((a.z + b.z) * rl);
  u.w = f2bf((a.w + b.w) * rl);
  reinterpret_cast<ushort4*>(Hb)[i] = u;
}

// ---------------------------------------------------------------- launch
extern "C" void kernel_launch(void* const* d_in, const int* in_sizes, int n_in,
                              void* d_out, int out_size, void* d_ws, size_t ws_size,
                              hipStream_t stream) {
  const float* x    = (const float*)d_in[0];
  const float* Wqkv = (const float*)d_in[1];
  const float* bqkv = (const float*)d_in[2];
  const float* qg   = (const float*)d_in[3];
  const float* kg   = (const float*)d_in[4];
  const float* Wout = (const float*)d_in[5];
  const float* bout = (const float*)d_in[6];
  float* out = (float*)d_out;

  char* ws = (char*)d_ws;
  unsigned short* xb  = (unsigned short*)(ws);
  unsigned short* w1b = (unsigned short*)(ws + ((size_t)8  << 20));
  unsigned short* w2b = (unsigned short*)(ws + ((size_t)14 << 20));
  float*          qkv = (float*)         (ws + ((size_t)16 << 20));  // dead after rmsnorm
  float*          Op  = (float*)         (ws + ((size_t)16 << 20));  // reuses qkv region (32MB)
  float*          Lp  = (float*)         (ws + ((size_t)48 << 20));  // 0.5MB
  unsigned short* Qn  = (unsigned short*)(ws + ((size_t)64 << 20));
  unsigned short* Kn  = (unsigned short*)(ws + ((size_t)72 << 20));
  unsigned short* Vt  = (unsigned short*)(ws + ((size_t)80 << 20));
  unsigned short* Hb  = (unsigned short*)(ws + ((size_t)88 << 20));

  pack_bf16_kernel<<<8192, 256, 0, stream>>>(x, Wqkv, Wout, xb, w1b, w2b);
  gemm_bt_kernel<<<dim3(32, 24), 256, 0, stream>>>(xb, w1b, bqkv, qkv,
                                                   N_TOK, 3 * CDIM, CDIM);
  rmsnorm_kernel<<<dim3(64, 16), 256, 0, stream>>>(qkv, qg, kg, Qn, Kn, Vt);
  flash_kernel<<<dim3(32, 16, 2), 256, 0, stream>>>(Qn, Kn, Vt, Op, Lp);
  combine_kernel<<<4096, 256, 0, stream>>>(Op, Lp, Hb);
  gemm_bt_kernel<<<dim3(32, 8), 256, 0, stream>>>(Hb, w2b, bout, out,
                                                  N_TOK, CDIM, CDIM);
}

// Round 7
// 146.382 us; speedup vs baseline: 1.4406x; 1.2309x over previous
//
#include <hip/hip_runtime.h>
#include <math.h>

#define N_TOK 4096
#define CDIM  1024
#define NH    16
#define HD    64

// scores: |q̂γ · k̂γ√D| <= 8 (γ=1), folded to log2 domain via K scale.
#define KSCALE 11.5416469f   // 8 * log2(e)

typedef __attribute__((ext_vector_type(8)))  __bf16 bf16x8;
typedef __attribute__((ext_vector_type(4)))  float  f32x4;
typedef __attribute__((ext_vector_type(16))) float  f32x16;
typedef __attribute__((ext_vector_type(4)))  unsigned int u32x4;

__device__ __forceinline__ unsigned short f2bf(float f) {
  unsigned int u = __builtin_bit_cast(unsigned int, f);
  u += 0x7FFFu + ((u >> 16) & 1u);            // RTNE
  return (unsigned short)(u >> 16);
}

__device__ __forceinline__ unsigned int cvt_pk_bf16(float lo, float hi) {
  unsigned int w;
  asm("v_cvt_pk_bf16_f32 %0, %1, %2" : "=v"(w) : "v"(lo), "v"(hi));
  return w;
}

// bare v_exp_f32 — inputs are in [-12, 12], no denormal handling needed
__device__ __forceinline__ float fexp2(float x) {
#if __has_builtin(__builtin_amdgcn_exp2f)
  return __builtin_amdgcn_exp2f(x);
#else
  return exp2f(x);
#endif
}

__device__ __forceinline__ void gload_lds16(const void* g, void* lds) {
  __builtin_amdgcn_global_load_lds(
      (const __attribute__((address_space(1))) unsigned int*)g,
      (__attribute__((address_space(3))) unsigned int*)lds, 16, 0, 0);
}

// ---------------------------------------------------------------- pack fp32->bf16
__global__ __launch_bounds__(256) void pack_bf16_kernel(
    const float* __restrict__ x, const float* __restrict__ w1,
    const float* __restrict__ w2, unsigned short* __restrict__ xb,
    unsigned short* __restrict__ w1b, unsigned short* __restrict__ w2b) {
  const size_t X4 = (size_t)N_TOK * CDIM / 4;
  const size_t W14 = (size_t)3 * CDIM * CDIM / 4;
  const size_t W24 = (size_t)CDIM * CDIM / 4;
  size_t i = (size_t)blockIdx.x * blockDim.x + threadIdx.x;
  const float* src; unsigned short* dst; size_t off;
  if (i < X4)              { src = x;  dst = xb;  off = i; }
  else if (i < X4 + W14)   { src = w1; dst = w1b; off = i - X4; }
  else if (i < X4 + W14 + W24) { src = w2; dst = w2b; off = i - X4 - W14; }
  else return;
  float4 v = reinterpret_cast<const float4*>(src)[off];
  ushort4 u;
  u.x = f2bf(v.x); u.y = f2bf(v.y); u.z = f2bf(v.z); u.w = f2bf(v.w);
  reinterpret_cast<ushort4*>(dst)[off] = u;
}

// ---------------------------------------------------------------- bf16 GEMM, C = A * B^T + bias (fp32 out)
__global__ __launch_bounds__(256, 2) void gemm_bt_kernel(
    const unsigned short* __restrict__ A, const unsigned short* __restrict__ B,
    const float* __restrict__ bias, float* __restrict__ C,
    int M, int Ncols, int K) {
  __shared__ alignas(16) char As[128 * 128];
  __shared__ alignas(16) char Bs[128 * 128];
  const int t = threadIdx.x;
  const int lane = t & 63, wave = t >> 6;
  const int wr = wave >> 1, wc = wave & 1;
  const int lrow = lane & 15, lk = lane >> 4;
  const int row0 = blockIdx.x * 128, col0 = blockIdx.y * 128;
  const f32x4 fzero = {0.f, 0.f, 0.f, 0.f};

  f32x4 acc[4][4];
#pragma unroll
  for (int m = 0; m < 4; ++m)
#pragma unroll
    for (int n = 0; n < 4; ++n) acc[m][n] = fzero;

  const int p_row = (t * 16) >> 7;
  const int p_cb  = (t * 16) & 127;

  for (int kt = 0; kt < K; kt += 64) {
    __syncthreads();
#pragma unroll
    for (int c = 0; c < 4; ++c) {
      int row = c * 32 + p_row;
      int kb = p_cb ^ ((row & 7) << 4);
      const char* gA = (const char*)A + ((size_t)(row0 + row) * K + kt) * 2 + kb;
      const char* gB = (const char*)B + ((size_t)(col0 + row) * K + kt) * 2 + kb;
      gload_lds16(gA, As + c * 4096 + wave * 1024);
      gload_lds16(gB, Bs + c * 4096 + wave * 1024);
    }
    __syncthreads();
#pragma unroll
    for (int kk = 0; kk < 2; ++kk) {
      bf16x8 a[4], b[4];
#pragma unroll
      for (int m = 0; m < 4; ++m) {
        int r = wr * 64 + m * 16 + lrow;
        a[m] = *reinterpret_cast<const bf16x8*>(
            As + r * 128 + ((kk * 64 + lk * 16) ^ ((r & 7) << 4)));
      }
#pragma unroll
      for (int n = 0; n < 4; ++n) {
        int r = wc * 64 + n * 16 + lrow;
        b[n] = *reinterpret_cast<const bf16x8*>(
            Bs + r * 128 + ((kk * 64 + lk * 16) ^ ((r & 7) << 4)));
      }
#pragma unroll
      for (int m = 0; m < 4; ++m)
#pragma unroll
        for (int n = 0; n < 4; ++n)
          acc[m][n] = __builtin_amdgcn_mfma_f32_16x16x32_bf16(a[m], b[n], acc[m][n], 0, 0, 0);
    }
  }

#pragma unroll
  for (int m = 0; m < 4; ++m) {
    int row = row0 + wr * 64 + m * 16 + lk * 4;
#pragma unroll
    for (int n = 0; n < 4; ++n) {
      int col = col0 + wc * 64 + n * 16 + lrow;
      float bv = bias[col];
#pragma unroll
      for (int j = 0; j < 4; ++j)
        C[(size_t)(row + j) * Ncols + col] = acc[m][n][j] + bv;
    }
  }
}

// ---------------------------------------------------------------- QKV GEMM with fused RMS-norm epilogue
// Computes qkv = x@Wqkv^T + b, then in-epilogue:
//   q -> Qn [H][N][D] bf16 = q̂*gamma
//   k -> Kn [H][N][D] bf16 = k̂*gamma * 8*log2e
//   v -> Vt [H][D][N'] bf16, N' = token idx with bits2<->3 swapped
// Each wave's 64-col span = exactly one head's full D; norm reduce is a
// 16-lane shfl_xor tree over lrow.
__global__ __launch_bounds__(256, 2) void gemm_qkv_kernel(
    const unsigned short* __restrict__ A, const unsigned short* __restrict__ B,
    const float* __restrict__ bias, const float* __restrict__ qg,
    const float* __restrict__ kg, unsigned short* __restrict__ Qn,
    unsigned short* __restrict__ Kn, unsigned short* __restrict__ Vt) {
  __shared__ alignas(16) char As[128 * 128];
  __shared__ alignas(16) char Bs[128 * 128];
  const int t = threadIdx.x;
  const int lane = t & 63, wave = t >> 6;
  const int wr = wave >> 1, wc = wave & 1;
  const int lrow = lane & 15, lk = lane >> 4;
  const int row0 = blockIdx.x * 128, col0 = blockIdx.y * 128;
  const int K = CDIM;
  const f32x4 fzero = {0.f, 0.f, 0.f, 0.f};

  f32x4 acc[4][4];
#pragma unroll
  for (int m = 0; m < 4; ++m)
#pragma unroll
    for (int n = 0; n < 4; ++n) acc[m][n] = fzero;

  const int p_row = (t * 16) >> 7;
  const int p_cb  = (t * 16) & 127;

  for (int kt = 0; kt < K; kt += 64) {
    __syncthreads();
#pragma unroll
    for (int c = 0; c < 4; ++c) {
      int row = c * 32 + p_row;
      int kb = p_cb ^ ((row & 7) << 4);
      const char* gA = (const char*)A + ((size_t)(row0 + row) * K + kt) * 2 + kb;
      const char* gB = (const char*)B + ((size_t)(col0 + row) * K + kt) * 2 + kb;
      gload_lds16(gA, As + c * 4096 + wave * 1024);
      gload_lds16(gB, Bs + c * 4096 + wave * 1024);
    }
    __syncthreads();
#pragma unroll
    for (int kk = 0; kk < 2; ++kk) {
      bf16x8 a[4], b[4];
#pragma unroll
      for (int m = 0; m < 4; ++m) {
        int r = wr * 64 + m * 16 + lrow;
        a[m] = *reinterpret_cast<const bf16x8*>(
            As + r * 128 + ((kk * 64 + lk * 16) ^ ((r & 7) << 4)));
      }
#pragma unroll
      for (int n = 0; n < 4; ++n) {
        int r = wc * 64 + n * 16 + lrow;
        b[n] = *reinterpret_cast<const bf16x8*>(
            Bs + r * 128 + ((kk * 64 + lk * 16) ^ ((r & 7) << 4)));
      }
#pragma unroll
      for (int m = 0; m < 4; ++m)
#pragma unroll
        for (int n = 0; n < 4; ++n)
          acc[m][n] = __builtin_amdgcn_mfma_f32_16x16x32_bf16(a[m], b[n], acc[m][n], 0, 0, 0);
    }
  }

  // ---- fused epilogue ----
  const int typ  = col0 >> 10;                       // 0=q 1=k 2=v (block-uniform)
  const int hloc = (((col0 & 1023) >> 6) + wc) & 15; // head for this wave
  float bv[4];
#pragma unroll
  for (int n = 0; n < 4; ++n) bv[n] = bias[col0 + wc * 64 + n * 16 + lrow];

  if (typ == 2) {
    // v: bf16 transpose-store, token bits2<->3 swapped (PV slot->key map)
#pragma unroll
    for (int m = 0; m < 4; ++m)
#pragma unroll
      for (int j = 0; j < 4; ++j) {
        int row = row0 + wr * 64 + m * 16 + lk * 4 + j;
        int np = (row & ~12) | ((row & 4) << 1) | ((row & 8) >> 1);
#pragma unroll
        for (int n = 0; n < 4; ++n) {
          int d = n * 16 + lrow;
          Vt[(size_t)(hloc * HD + d) * N_TOK + np] = f2bf(acc[m][n][j] + bv[n]);
        }
      }
  } else {
    const float* g = (typ == 0) ? qg : kg;
    const float gscale = (typ == 0) ? 1.0f : KSCALE;
    unsigned short* dst = (typ == 0) ? Qn : Kn;
    float gv[4];
#pragma unroll
    for (int n = 0; n < 4; ++n)
      gv[n] = g[hloc * HD + n * 16 + lrow] * gscale;
#pragma unroll
    for (int m = 0; m < 4; ++m)
#pragma unroll
      for (int j = 0; j < 4; ++j) {
        float tv[4];
        float ss = 0.f;
#pragma unroll
        for (int n = 0; n < 4; ++n) {
          tv[n] = acc[m][n][j] + bv[n];
          ss += tv[n] * tv[n];
        }
        // reduce over d: lanes sharing lk (lrow = 0..15)
        ss += __shfl_xor(ss, 1);
        ss += __shfl_xor(ss, 2);
        ss += __shfl_xor(ss, 4);
        ss += __shfl_xor(ss, 8);
        float r = rsqrtf(fmaxf(ss, 1e-24f));
        int row = row0 + wr * 64 + m * 16 + lk * 4 + j;
#pragma unroll
        for (int n = 0; n < 4; ++n)
          dst[((size_t)hloc * N_TOK + row) * HD + n * 16 + lrow] =
              f2bf(tv[n] * r * gv[n]);
      }
  }
}

// ---------------------------------------------------------------- flash attention v6
// split-KV (blockIdx.z), sequenced 32-key halves, bare v_exp_f32 softmax,
// hoisted lane-invariant LDS offsets + pointer-increment staging.
__global__ __launch_bounds__(256, 4) void flash_kernel(
    const unsigned short* __restrict__ Qn, const unsigned short* __restrict__ Kn,
    const unsigned short* __restrict__ Vt, float* __restrict__ Op,
    float* __restrict__ Lp) {
  __shared__ alignas(16) char Ks[2][64 * 128];
  __shared__ alignas(16) char Vs[2][64 * 128];
  const int t = threadIdx.x, lane = t & 63, wave = t >> 6;
  const int q = lane & 31, hi = lane >> 5;
  const int h = blockIdx.y;
  const int half = blockIdx.z;
  const int q0 = blockIdx.x * 128 + wave * 32;
  const int kv0 = half << 11;

  bf16x8 bq[4];
#pragma unroll
  for (int c = 0; c < 4; ++c)
    bq[c] = *reinterpret_cast<const bf16x8*>(
        Qn + ((size_t)h * N_TOK + q0 + q) * HD + c * 16 + hi * 8);

  f32x16 ot0, ot1;
#pragma unroll
  for (int r = 0; r < 16; ++r) { ot0[r] = 0.f; ot1[r] = 0.f; }
  float l = 0.f;

  // loop-invariant swizzled LDS read offsets (lane constants)
  int koff[4], voff[4];
#pragma unroll
  for (int c = 0; c < 4; ++c)
    koff[c] = q * 128 + ((c * 32 + hi * 16) ^ ((q & 7) << 4));
#pragma unroll
  for (int kt = 0; kt < 4; ++kt)
    voff[kt] = q * 128 + ((kt * 32 + hi * 16) ^ ((q & 7) << 4));

  // persistent staging pointers, advanced per tile
  const int p_row = (t * 16) >> 7;
  const int p_cb  = (t * 16) & 127;
  const int scb   = p_cb ^ ((p_row & 7) << 4);
  const char* gK0 = (const char*)Kn + ((size_t)h * N_TOK + kv0 + p_row) * 128 + scb;
  const char* gK1 = gK0 + 32 * 128;
  const char* gV0 = (const char*)Vt + ((size_t)(h * HD + p_row) * N_TOK + kv0) * 2 + scb;
  const char* gV1 = gV0 + (size_t)32 * N_TOK * 2;

  auto stage = [&](int b) {
    char* dK = Ks[b] + wave * 1024;
    char* dV = Vs[b] + wave * 1024;
    gload_lds16(gK0, dK);
    gload_lds16(gK1, dK + 4096);
    gload_lds16(gV0, dV);
    gload_lds16(gV1, dV + 4096);
    gK0 += 8192; gK1 += 8192; gV0 += 128; gV1 += 128;
  };

  stage(0);
  int buf = 0;

  for (int kv = kv0; kv < kv0 + 2048; kv += 64) {
    __syncthreads();
    if (kv + 64 < kv0 + 2048) stage(buf ^ 1);

    const char* Kb = Ks[buf];
    const char* Vb = Vs[buf];

#pragma unroll
    for (int hblk = 0; hblk < 2; ++hblk) {      // keys hblk*32 .. hblk*32+31
      f32x16 s;
#pragma unroll
      for (int r = 0; r < 16; ++r) s[r] = 0.f;
      __builtin_amdgcn_s_setprio(1);
#pragma unroll
      for (int c = 0; c < 4; ++c) {
        bf16x8 kf = *reinterpret_cast<const bf16x8*>(Kb + koff[c] + hblk * 4096);
        s = __builtin_amdgcn_mfma_f32_32x32x16_bf16(kf, bq[c], s, 0, 0, 0);
      }
      __builtin_amdgcn_s_setprio(0);

      float ps = 0.f;
      unsigned int W[8];
#pragma unroll
      for (int i = 0; i < 8; ++i) {
        float p0 = fexp2(s[2 * i]);
        float p1 = fexp2(s[2 * i + 1]);
        W[i] = cvt_pk_bf16(p0, p1);
        ps += p0 + p1;
      }
      l += ps;

      __builtin_amdgcn_s_setprio(1);
#pragma unroll
      for (int ktl = 0; ktl < 2; ++ktl) {       // key-subtiles of 16
        const int kt = hblk * 2 + ktl;
        u32x4 pw;
#pragma unroll
        for (int i = 0; i < 4; ++i) pw[i] = W[ktl * 4 + i];
        bf16x8 pfrag = __builtin_bit_cast(bf16x8, pw);
        bf16x8 vf0 = *reinterpret_cast<const bf16x8*>(Vb + voff[kt]);
        ot0 = __builtin_amdgcn_mfma_f32_32x32x16_bf16(vf0, pfrag, ot0, 0, 0, 0);
        bf16x8 vf1 = *reinterpret_cast<const bf16x8*>(Vb + voff[kt] + 4096);
        ot1 = __builtin_amdgcn_mfma_f32_32x32x16_bf16(vf1, pfrag, ot1, 0, 0, 0);
      }
      __builtin_amdgcn_s_setprio(0);
    }
    buf ^= 1;
  }

  // un-normalized partial out (fp32) + denominator partial
  float* ob = Op + ((size_t)half * N_TOK + q0 + q) * CDIM + h * HD;
#pragma unroll
  for (int g = 0; g < 4; ++g) {
    float4 v0 = {ot0[4 * g + 0], ot0[4 * g + 1], ot0[4 * g + 2], ot0[4 * g + 3]};
    float4 v1 = {ot1[4 * g + 0], ot1[4 * g + 1], ot1[4 * g + 2], ot1[4 * g + 3]};
    *reinterpret_cast<float4*>(ob + g * 8 + hi * 4) = v0;
    *reinterpret_cast<float4*>(ob + 32 + g * 8 + hi * 4) = v1;
  }
  l += __shfl_xor(l, 32);
  if (hi == 0)
    Lp[((size_t)half * NH + h) * N_TOK + q0 + q] = l;
}

// ---------------------------------------------------------------- combine halves -> bf16 Hb
__global__ __launch_bounds__(256) void combine_kernel(
    const float* __restrict__ Op, const float* __restrict__ Lp,
    unsigned short* __restrict__ Hb) {
  int i = blockIdx.x * 256 + threadIdx.x;          // float4 index, N*C/4 total
  int c = (i & (CDIM / 4 - 1)) * 4;
  int n = i >> 8;
  int h = c >> 6;
  float l0 = Lp[(size_t)h * N_TOK + n];
  float l1 = Lp[((size_t)NH + h) * N_TOK + n];
  float rl = 1.0f / (l0 + l1);
  float4 a = reinterpret_cast<const float4*>(Op)[i];
  float4 b = reinterpret_cast<const float4*>(Op + (size_t)N_TOK * CDIM)[i];
  ushort4 u;
  u.x = f2bf((a.x + b.x) * rl);
  u.y = f2bf((a.y + b.y) * rl);
  u.z = f2bf((a.z + b.z) * rl);
  u.w = f2bf((a.w + b.w) * rl);
  reinterpret_cast<ushort4*>(Hb)[i] = u;
}

// ---------------------------------------------------------------- launch
extern "C" void kernel_launch(void* const* d_in, const int* in_sizes, int n_in,
                              void* d_out, int out_size, void* d_ws, size_t ws_size,
                              hipStream_t stream) {
  const float* x    = (const float*)d_in[0];
  const float* Wqkv = (const float*)d_in[1];
  const float* bqkv = (const float*)d_in[2];
  const float* qg   = (const float*)d_in[3];
  const float* kg   = (const float*)d_in[4];
  const float* Wout = (const float*)d_in[5];
  const float* bout = (const float*)d_in[6];
  float* out = (float*)d_out;

  char* ws = (char*)d_ws;
  unsigned short* xb  = (unsigned short*)(ws);
  unsigned short* w1b = (unsigned short*)(ws + ((size_t)8  << 20));
  unsigned short* w2b = (unsigned short*)(ws + ((size_t)14 << 20));
  float*          Op  = (float*)         (ws + ((size_t)16 << 20));  // 32MB
  float*          Lp  = (float*)         (ws + ((size_t)48 << 20));  // 0.5MB
  unsigned short* Qn  = (unsigned short*)(ws + ((size_t)64 << 20));
  unsigned short* Kn  = (unsigned short*)(ws + ((size_t)72 << 20));
  unsigned short* Vt  = (unsigned short*)(ws + ((size_t)80 << 20));
  unsigned short* Hb  = (unsigned short*)(ws + ((size_t)88 << 20));

  pack_bf16_kernel<<<8192, 256, 0, stream>>>(x, Wqkv, Wout, xb, w1b, w2b);
  gemm_qkv_kernel<<<dim3(32, 24), 256, 0, stream>>>(xb, w1b, bqkv, qg, kg,
                                                    Qn, Kn, Vt);
  flash_kernel<<<dim3(32, 16, 2), 256, 0, stream>>>(Qn, Kn, Vt, Op, Lp);
  combine_kernel<<<4096, 256, 0, stream>>>(Op, Lp, Hb);
  gemm_bt_kernel<<<dim3(32, 8), 256, 0, stream>>>(Hb, w2b, bout, out,
                                                  N_TOK, CDIM, CDIM);
}

// Round 8
// 144.882 us; speedup vs baseline: 1.4556x; 1.0104x over previous
//
#include <hip/hip_runtime.h>
#include <math.h>

#define N_TOK 4096
#define CDIM  1024
#define NH    16
#define HD    64

// scores: |q̂γ · k̂γ√D| <= 8 (γ=1), folded to log2 domain via K scale.
#define KSCALE 11.5416469f   // 8 * log2(e)

typedef __attribute__((ext_vector_type(8)))  __bf16 bf16x8;
typedef __attribute__((ext_vector_type(4)))  float  f32x4;
typedef __attribute__((ext_vector_type(16))) float  f32x16;
typedef __attribute__((ext_vector_type(4)))  unsigned int u32x4;

__device__ __forceinline__ unsigned short f2bf(float f) {
  unsigned int u = __builtin_bit_cast(unsigned int, f);
  u += 0x7FFFu + ((u >> 16) & 1u);            // RTNE
  return (unsigned short)(u >> 16);
}

__device__ __forceinline__ unsigned int cvt_pk_bf16(float lo, float hi) {
  unsigned int w;
  asm("v_cvt_pk_bf16_f32 %0, %1, %2" : "=v"(w) : "v"(lo), "v"(hi));
  return w;
}

// bare v_exp_f32 — inputs are in [-12, 12], no denormal handling needed
__device__ __forceinline__ float fexp2(float x) {
#if __has_builtin(__builtin_amdgcn_exp2f)
  return __builtin_amdgcn_exp2f(x);
#else
  return exp2f(x);
#endif
}

__device__ __forceinline__ void gload_lds16(const void* g, void* lds) {
  __builtin_amdgcn_global_load_lds(
      (const __attribute__((address_space(1))) unsigned int*)g,
      (__attribute__((address_space(3))) unsigned int*)lds, 16, 0, 0);
}

// ---------------------------------------------------------------- pack fp32->bf16
__global__ __launch_bounds__(256) void pack_bf16_kernel(
    const float* __restrict__ x, const float* __restrict__ w1,
    const float* __restrict__ w2, unsigned short* __restrict__ xb,
    unsigned short* __restrict__ w1b, unsigned short* __restrict__ w2b) {
  const size_t X4 = (size_t)N_TOK * CDIM / 4;
  const size_t W14 = (size_t)3 * CDIM * CDIM / 4;
  const size_t W24 = (size_t)CDIM * CDIM / 4;
  size_t i = (size_t)blockIdx.x * blockDim.x + threadIdx.x;
  const float* src; unsigned short* dst; size_t off;
  if (i < X4)              { src = x;  dst = xb;  off = i; }
  else if (i < X4 + W14)   { src = w1; dst = w1b; off = i - X4; }
  else if (i < X4 + W14 + W24) { src = w2; dst = w2b; off = i - X4 - W14; }
  else return;
  float4 v = reinterpret_cast<const float4*>(src)[off];
  ushort4 u;
  u.x = f2bf(v.x); u.y = f2bf(v.y); u.z = f2bf(v.z); u.w = f2bf(v.w);
  reinterpret_cast<ushort4*>(dst)[off] = u;
}

// ---------------------------------------------------------------- bf16 GEMM, C = A * B^T + bias (fp32 out)
__global__ __launch_bounds__(256, 2) void gemm_bt_kernel(
    const unsigned short* __restrict__ A, const unsigned short* __restrict__ B,
    const float* __restrict__ bias, float* __restrict__ C,
    int M, int Ncols, int K) {
  __shared__ alignas(16) char As[128 * 128];
  __shared__ alignas(16) char Bs[128 * 128];
  const int t = threadIdx.x;
  const int lane = t & 63, wave = t >> 6;
  const int wr = wave >> 1, wc = wave & 1;
  const int lrow = lane & 15, lk = lane >> 4;
  const int row0 = blockIdx.x * 128, col0 = blockIdx.y * 128;
  const f32x4 fzero = {0.f, 0.f, 0.f, 0.f};

  f32x4 acc[4][4];
#pragma unroll
  for (int m = 0; m < 4; ++m)
#pragma unroll
    for (int n = 0; n < 4; ++n) acc[m][n] = fzero;

  const int p_row = (t * 16) >> 7;
  const int p_cb  = (t * 16) & 127;

  for (int kt = 0; kt < K; kt += 64) {
    __syncthreads();
#pragma unroll
    for (int c = 0; c < 4; ++c) {
      int row = c * 32 + p_row;
      int kb = p_cb ^ ((row & 7) << 4);
      const char* gA = (const char*)A + ((size_t)(row0 + row) * K + kt) * 2 + kb;
      const char* gB = (const char*)B + ((size_t)(col0 + row) * K + kt) * 2 + kb;
      gload_lds16(gA, As + c * 4096 + wave * 1024);
      gload_lds16(gB, Bs + c * 4096 + wave * 1024);
    }
    __syncthreads();
#pragma unroll
    for (int kk = 0; kk < 2; ++kk) {
      bf16x8 a[4], b[4];
#pragma unroll
      for (int m = 0; m < 4; ++m) {
        int r = wr * 64 + m * 16 + lrow;
        a[m] = *reinterpret_cast<const bf16x8*>(
            As + r * 128 + ((kk * 64 + lk * 16) ^ ((r & 7) << 4)));
      }
#pragma unroll
      for (int n = 0; n < 4; ++n) {
        int r = wc * 64 + n * 16 + lrow;
        b[n] = *reinterpret_cast<const bf16x8*>(
            Bs + r * 128 + ((kk * 64 + lk * 16) ^ ((r & 7) << 4)));
      }
#pragma unroll
      for (int m = 0; m < 4; ++m)
#pragma unroll
        for (int n = 0; n < 4; ++n)
          acc[m][n] = __builtin_amdgcn_mfma_f32_16x16x32_bf16(a[m], b[n], acc[m][n], 0, 0, 0);
    }
  }

#pragma unroll
  for (int m = 0; m < 4; ++m) {
    int row = row0 + wr * 64 + m * 16 + lk * 4;
#pragma unroll
    for (int n = 0; n < 4; ++n) {
      int col = col0 + wc * 64 + n * 16 + lrow;
      float bv = bias[col];
#pragma unroll
      for (int j = 0; j < 4; ++j)
        C[(size_t)(row + j) * Ncols + col] = acc[m][n][j] + bv;
    }
  }
}

// ---------------------------------------------------------------- QKV GEMM with fused RMS-norm epilogue
__global__ __launch_bounds__(256, 2) void gemm_qkv_kernel(
    const unsigned short* __restrict__ A, const unsigned short* __restrict__ B,
    const float* __restrict__ bias, const float* __restrict__ qg,
    const float* __restrict__ kg, unsigned short* __restrict__ Qn,
    unsigned short* __restrict__ Kn, unsigned short* __restrict__ Vt) {
  __shared__ alignas(16) char As[128 * 128];
  __shared__ alignas(16) char Bs[128 * 128];
  const int t = threadIdx.x;
  const int lane = t & 63, wave = t >> 6;
  const int wr = wave >> 1, wc = wave & 1;
  const int lrow = lane & 15, lk = lane >> 4;
  const int row0 = blockIdx.x * 128, col0 = blockIdx.y * 128;
  const int K = CDIM;
  const f32x4 fzero = {0.f, 0.f, 0.f, 0.f};

  f32x4 acc[4][4];
#pragma unroll
  for (int m = 0; m < 4; ++m)
#pragma unroll
    for (int n = 0; n < 4; ++n) acc[m][n] = fzero;

  const int p_row = (t * 16) >> 7;
  const int p_cb  = (t * 16) & 127;

  for (int kt = 0; kt < K; kt += 64) {
    __syncthreads();
#pragma unroll
    for (int c = 0; c < 4; ++c) {
      int row = c * 32 + p_row;
      int kb = p_cb ^ ((row & 7) << 4);
      const char* gA = (const char*)A + ((size_t)(row0 + row) * K + kt) * 2 + kb;
      const char* gB = (const char*)B + ((size_t)(col0 + row) * K + kt) * 2 + kb;
      gload_lds16(gA, As + c * 4096 + wave * 1024);
      gload_lds16(gB, Bs + c * 4096 + wave * 1024);
    }
    __syncthreads();
#pragma unroll
    for (int kk = 0; kk < 2; ++kk) {
      bf16x8 a[4], b[4];
#pragma unroll
      for (int m = 0; m < 4; ++m) {
        int r = wr * 64 + m * 16 + lrow;
        a[m] = *reinterpret_cast<const bf16x8*>(
            As + r * 128 + ((kk * 64 + lk * 16) ^ ((r & 7) << 4)));
      }
#pragma unroll
      for (int n = 0; n < 4; ++n) {
        int r = wc * 64 + n * 16 + lrow;
        b[n] = *reinterpret_cast<const bf16x8*>(
            Bs + r * 128 + ((kk * 64 + lk * 16) ^ ((r & 7) << 4)));
      }
#pragma unroll
      for (int m = 0; m < 4; ++m)
#pragma unroll
        for (int n = 0; n < 4; ++n)
          acc[m][n] = __builtin_amdgcn_mfma_f32_16x16x32_bf16(a[m], b[n], acc[m][n], 0, 0, 0);
    }
  }

  // ---- fused epilogue ----
  const int typ  = col0 >> 10;                       // 0=q 1=k 2=v (block-uniform)
  const int hloc = (((col0 & 1023) >> 6) + wc) & 15; // head for this wave
  float bv[4];
#pragma unroll
  for (int n = 0; n < 4; ++n) bv[n] = bias[col0 + wc * 64 + n * 16 + lrow];

  if (typ == 2) {
#pragma unroll
    for (int m = 0; m < 4; ++m)
#pragma unroll
      for (int j = 0; j < 4; ++j) {
        int row = row0 + wr * 64 + m * 16 + lk * 4 + j;
        int np = (row & ~12) | ((row & 4) << 1) | ((row & 8) >> 1);
#pragma unroll
        for (int n = 0; n < 4; ++n) {
          int d = n * 16 + lrow;
          Vt[(size_t)(hloc * HD + d) * N_TOK + np] = f2bf(acc[m][n][j] + bv[n]);
        }
      }
  } else {
    const float* g = (typ == 0) ? qg : kg;
    const float gscale = (typ == 0) ? 1.0f : KSCALE;
    unsigned short* dst = (typ == 0) ? Qn : Kn;
    float gv[4];
#pragma unroll
    for (int n = 0; n < 4; ++n)
      gv[n] = g[hloc * HD + n * 16 + lrow] * gscale;
#pragma unroll
    for (int m = 0; m < 4; ++m)
#pragma unroll
      for (int j = 0; j < 4; ++j) {
        float tv[4];
        float ss = 0.f;
#pragma unroll
        for (int n = 0; n < 4; ++n) {
          tv[n] = acc[m][n][j] + bv[n];
          ss += tv[n] * tv[n];
        }
        ss += __shfl_xor(ss, 1);
        ss += __shfl_xor(ss, 2);
        ss += __shfl_xor(ss, 4);
        ss += __shfl_xor(ss, 8);
        float r = rsqrtf(fmaxf(ss, 1e-24f));
        int row = row0 + wr * 64 + m * 16 + lk * 4 + j;
#pragma unroll
        for (int n = 0; n < 4; ++n)
          dst[((size_t)hloc * N_TOK + row) * HD + n * 16 + lrow] =
              f2bf(tv[n] * r * gv[n]);
      }
  }
}

// ---------------------------------------------------------------- flash attention v7
// split-KV, sequenced 32-key halves, bare v_exp_f32 softmax.
// T14 async-STAGE: global->reg loads issued at tile start (next tile),
// ds_write just before the barrier -> HBM latency hides under compute,
// barrier no longer drains global loads.
__global__ __launch_bounds__(256, 4) void flash_kernel(
    const unsigned short* __restrict__ Qn, const unsigned short* __restrict__ Kn,
    const unsigned short* __restrict__ Vt, float* __restrict__ Op,
    float* __restrict__ Lp) {
  __shared__ alignas(16) char Ks[2][64 * 128];
  __shared__ alignas(16) char Vs[2][64 * 128];
  const int t = threadIdx.x, lane = t & 63, wave = t >> 6;
  const int q = lane & 31, hi = lane >> 5;
  const int h = blockIdx.y;
  const int half = blockIdx.z;
  const int q0 = blockIdx.x * 128 + wave * 32;
  const int kv0 = half << 11;

  bf16x8 bq[4];
#pragma unroll
  for (int c = 0; c < 4; ++c)
    bq[c] = *reinterpret_cast<const bf16x8*>(
        Qn + ((size_t)h * N_TOK + q0 + q) * HD + c * 16 + hi * 8);

  f32x16 ot0, ot1;
#pragma unroll
  for (int r = 0; r < 16; ++r) { ot0[r] = 0.f; ot1[r] = 0.f; }
  float l = 0.f;

  // loop-invariant swizzled LDS read offsets (lane constants)
  int koff[4], voff[4];
#pragma unroll
  for (int c = 0; c < 4; ++c)
    koff[c] = q * 128 + ((c * 32 + hi * 16) ^ ((q & 7) << 4));
#pragma unroll
  for (int kt = 0; kt < 4; ++kt)
    voff[kt] = q * 128 + ((kt * 32 + hi * 16) ^ ((q & 7) << 4));

  // persistent staging pointers (pre-swizzled source), advanced per tile
  const int p_row = (t * 16) >> 7;
  const int p_cb  = (t * 16) & 127;
  const int scb   = p_cb ^ ((p_row & 7) << 4);
  const char* gK0 = (const char*)Kn + ((size_t)h * N_TOK + kv0 + p_row) * 128 + scb;
  const char* gK1 = gK0 + 32 * 128;
  const char* gV0 = (const char*)Vt + ((size_t)(h * HD + p_row) * N_TOK + kv0) * 2 + scb;
  const char* gV1 = gV0 + (size_t)32 * N_TOK * 2;

  u32x4 rK0, rK1, rV0, rV1;
  auto load_regs = [&]() {
    rK0 = *reinterpret_cast<const u32x4*>(gK0);
    rK1 = *reinterpret_cast<const u32x4*>(gK1);
    rV0 = *reinterpret_cast<const u32x4*>(gV0);
    rV1 = *reinterpret_cast<const u32x4*>(gV1);
    gK0 += 8192; gK1 += 8192; gV0 += 128; gV1 += 128;
  };
  auto write_lds = [&](int b) {
    *reinterpret_cast<u32x4*>(Ks[b] + t * 16)        = rK0;
    *reinterpret_cast<u32x4*>(Ks[b] + 4096 + t * 16) = rK1;
    *reinterpret_cast<u32x4*>(Vs[b] + t * 16)        = rV0;
    *reinterpret_cast<u32x4*>(Vs[b] + 4096 + t * 16) = rV1;
  };

  load_regs();
  write_lds(0);
  __syncthreads();
  int buf = 0;

  for (int kv = kv0; kv < kv0 + 2048; kv += 64) {
    const bool more = (kv + 64 < kv0 + 2048);
    if (more) load_regs();                 // issue next tile's loads NOW

    const char* Kb = Ks[buf];
    const char* Vb = Vs[buf];

#pragma unroll
    for (int hblk = 0; hblk < 2; ++hblk) {      // keys hblk*32 .. hblk*32+31
      f32x16 s;
#pragma unroll
      for (int r = 0; r < 16; ++r) s[r] = 0.f;
      __builtin_amdgcn_s_setprio(1);
#pragma unroll
      for (int c = 0; c < 4; ++c) {
        bf16x8 kf = *reinterpret_cast<const bf16x8*>(Kb + koff[c] + hblk * 4096);
        s = __builtin_amdgcn_mfma_f32_32x32x16_bf16(kf, bq[c], s, 0, 0, 0);
      }
      __builtin_amdgcn_s_setprio(0);

      float ps = 0.f;
      unsigned int W[8];
#pragma unroll
      for (int i = 0; i < 8; ++i) {
        float p0 = fexp2(s[2 * i]);
        float p1 = fexp2(s[2 * i + 1]);
        W[i] = cvt_pk_bf16(p0, p1);
        ps += p0 + p1;
      }
      l += ps;

      __builtin_amdgcn_s_setprio(1);
#pragma unroll
      for (int ktl = 0; ktl < 2; ++ktl) {       // key-subtiles of 16
        const int kt = hblk * 2 + ktl;
        u32x4 pw;
#pragma unroll
        for (int i = 0; i < 4; ++i) pw[i] = W[ktl * 4 + i];
        bf16x8 pfrag = __builtin_bit_cast(bf16x8, pw);
        bf16x8 vf0 = *reinterpret_cast<const bf16x8*>(Vb + voff[kt]);
        ot0 = __builtin_amdgcn_mfma_f32_32x32x16_bf16(vf0, pfrag, ot0, 0, 0, 0);
        bf16x8 vf1 = *reinterpret_cast<const bf16x8*>(Vb + voff[kt] + 4096);
        ot1 = __builtin_amdgcn_mfma_f32_32x32x16_bf16(vf1, pfrag, ot1, 0, 0, 0);
      }
      __builtin_amdgcn_s_setprio(0);
    }

    if (more) {
      write_lds(buf ^ 1);                  // compiler waits vmcnt just here
      __syncthreads();
      buf ^= 1;
    }
  }

  // un-normalized partial out (fp32) + denominator partial
  float* ob = Op + ((size_t)half * N_TOK + q0 + q) * CDIM + h * HD;
#pragma unroll
  for (int g = 0; g < 4; ++g) {
    float4 v0 = {ot0[4 * g + 0], ot0[4 * g + 1], ot0[4 * g + 2], ot0[4 * g + 3]};
    float4 v1 = {ot1[4 * g + 0], ot1[4 * g + 1], ot1[4 * g + 2], ot1[4 * g + 3]};
    *reinterpret_cast<float4*>(ob + g * 8 + hi * 4) = v0;
    *reinterpret_cast<float4*>(ob + 32 + g * 8 + hi * 4) = v1;
  }
  l += __shfl_xor(l, 32);
  if (hi == 0)
    Lp[((size_t)half * NH + h) * N_TOK + q0 + q] = l;
}

// ---------------------------------------------------------------- combine halves -> bf16 Hb
__global__ __launch_bounds__(256) void combine_kernel(
    const float* __restrict__ Op, const float* __restrict__ Lp,
    unsigned short* __restrict__ Hb) {
  int i = blockIdx.x * 256 + threadIdx.x;          // float4 index, N*C/4 total
  int c = (i & (CDIM / 4 - 1)) * 4;
  int n = i >> 8;
  int h = c >> 6;
  float l0 = Lp[(size_t)h * N_TOK + n];
  float l1 = Lp[((size_t)NH + h) * N_TOK + n];
  float rl = 1.0f / (l0 + l1);
  float4 a = reinterpret_cast<const float4*>(Op)[i];
  float4 b = reinterpret_cast<const float4*>(Op + (size_t)N_TOK * CDIM)[i];
  ushort4 u;
  u.x = f2bf((a.x + b.x) * rl);
  u.y = f2bf((a.y + b.y) * rl);
  u.z = f2bf((a.z + b.z) * rl);
  u.w = f2bf((a.w + b.w) * rl);
  reinterpret_cast<ushort4*>(Hb)[i] = u;
}

// ---------------------------------------------------------------- launch
extern "C" void kernel_launch(void* const* d_in, const int* in_sizes, int n_in,
                              void* d_out, int out_size, void* d_ws, size_t ws_size,
                              hipStream_t stream) {
  const float* x    = (const float*)d_in[0];
  const float* Wqkv = (const float*)d_in[1];
  const float* bqkv = (const float*)d_in[2];
  const float* qg   = (const float*)d_in[3];
  const float* kg   = (const float*)d_in[4];
  const float* Wout = (const float*)d_in[5];
  const float* bout = (const float*)d_in[6];
  float* out = (float*)d_out;

  char* ws = (char*)d_ws;
  unsigned short* xb  = (unsigned short*)(ws);
  unsigned short* w1b = (unsigned short*)(ws + ((size_t)8  << 20));
  unsigned short* w2b = (unsigned short*)(ws + ((size_t)14 << 20));
  float*          Op  = (float*)         (ws + ((size_t)16 << 20));  // 32MB
  float*          Lp  = (float*)         (ws + ((size_t)48 << 20));  // 0.5MB
  unsigned short* Qn  = (unsigned short*)(ws + ((size_t)64 << 20));
  unsigned short* Kn  = (unsigned short*)(ws + ((size_t)72 << 20));
  unsigned short* Vt  = (unsigned short*)(ws + ((size_t)80 << 20));
  unsigned short* Hb  = (unsigned short*)(ws + ((size_t)88 << 20));

  pack_bf16_kernel<<<8192, 256, 0, stream>>>(x, Wqkv, Wout, xb, w1b, w2b);
  gemm_qkv_kernel<<<dim3(32, 24), 256, 0, stream>>>(xb, w1b, bqkv, qg, kg,
                                                    Qn, Kn, Vt);
  flash_kernel<<<dim3(32, 16, 2), 256, 0, stream>>>(Qn, Kn, Vt, Op, Lp);
  combine_kernel<<<4096, 256, 0, stream>>>(Op, Lp, Hb);
  gemm_bt_kernel<<<dim3(32, 8), 256, 0, stream>>>(Hb, w2b, bout, out,
                                                  N_TOK, CDIM, CDIM);
}

// Round 9
// 144.103 us; speedup vs baseline: 1.4634x; 1.0054x over previous
//
#include <hip/hip_runtime.h>
#include <math.h>

#define N_TOK 4096
#define CDIM  1024
#define NH    16
#define HD    64

// scores: |q̂γ · k̂γ√D| <= 8 (γ=1), folded to log2 domain via K scale.
#define KSCALE 11.5416469f   // 8 * log2(e)

typedef __attribute__((ext_vector_type(8)))  __bf16 bf16x8;
typedef __attribute__((ext_vector_type(2)))  float  f32x2;
typedef __attribute__((ext_vector_type(4)))  float  f32x4;
typedef __attribute__((ext_vector_type(16))) float  f32x16;
typedef __attribute__((ext_vector_type(4)))  unsigned int u32x4;

__device__ __forceinline__ unsigned short f2bf(float f) {
  unsigned int u = __builtin_bit_cast(unsigned int, f);
  u += 0x7FFFu + ((u >> 16) & 1u);            // RTNE
  return (unsigned short)(u >> 16);
}

__device__ __forceinline__ unsigned int cvt_pk_bf16(float lo, float hi) {
  unsigned int w;
  asm("v_cvt_pk_bf16_f32 %0, %1, %2" : "=v"(w) : "v"(lo), "v"(hi));
  return w;
}

// bare v_exp_f32 — inputs are in [-12, 12], no denormal handling needed
__device__ __forceinline__ float fexp2(float x) {
#if __has_builtin(__builtin_amdgcn_exp2f)
  return __builtin_amdgcn_exp2f(x);
#else
  return exp2f(x);
#endif
}

__device__ __forceinline__ void gload_lds16(const void* g, void* lds) {
  __builtin_amdgcn_global_load_lds(
      (const __attribute__((address_space(1))) unsigned int*)g,
      (__attribute__((address_space(3))) unsigned int*)lds, 16, 0, 0);
}

// ---------------------------------------------------------------- pack fp32->bf16
__global__ __launch_bounds__(256) void pack_bf16_kernel(
    const float* __restrict__ x, const float* __restrict__ w1,
    const float* __restrict__ w2, unsigned short* __restrict__ xb,
    unsigned short* __restrict__ w1b, unsigned short* __restrict__ w2b) {
  const size_t X4 = (size_t)N_TOK * CDIM / 4;
  const size_t W14 = (size_t)3 * CDIM * CDIM / 4;
  const size_t W24 = (size_t)CDIM * CDIM / 4;
  size_t i = (size_t)blockIdx.x * blockDim.x + threadIdx.x;
  const float* src; unsigned short* dst; size_t off;
  if (i < X4)              { src = x;  dst = xb;  off = i; }
  else if (i < X4 + W14)   { src = w1; dst = w1b; off = i - X4; }
  else if (i < X4 + W14 + W24) { src = w2; dst = w2b; off = i - X4 - W14; }
  else return;
  float4 v = reinterpret_cast<const float4*>(src)[off];
  ushort4 u;
  u.x = f2bf(v.x); u.y = f2bf(v.y); u.z = f2bf(v.z); u.w = f2bf(v.w);
  reinterpret_cast<ushort4*>(dst)[off] = u;
}

// ---------------------------------------------------------------- bf16 GEMM, C = A * B^T + bias (fp32 out)
__global__ __launch_bounds__(256, 2) void gemm_bt_kernel(
    const unsigned short* __restrict__ A, const unsigned short* __restrict__ B,
    const float* __restrict__ bias, float* __restrict__ C,
    int M, int Ncols, int K) {
  __shared__ alignas(16) char As[128 * 128];
  __shared__ alignas(16) char Bs[128 * 128];
  const int t = threadIdx.x;
  const int lane = t & 63, wave = t >> 6;
  const int wr = wave >> 1, wc = wave & 1;
  const int lrow = lane & 15, lk = lane >> 4;
  const int row0 = blockIdx.x * 128, col0 = blockIdx.y * 128;
  const f32x4 fzero = {0.f, 0.f, 0.f, 0.f};

  f32x4 acc[4][4];
#pragma unroll
  for (int m = 0; m < 4; ++m)
#pragma unroll
    for (int n = 0; n < 4; ++n) acc[m][n] = fzero;

  const int p_row = (t * 16) >> 7;
  const int p_cb  = (t * 16) & 127;

  for (int kt = 0; kt < K; kt += 64) {
    __syncthreads();
#pragma unroll
    for (int c = 0; c < 4; ++c) {
      int row = c * 32 + p_row;
      int kb = p_cb ^ ((row & 7) << 4);
      const char* gA = (const char*)A + ((size_t)(row0 + row) * K + kt) * 2 + kb;
      const char* gB = (const char*)B + ((size_t)(col0 + row) * K + kt) * 2 + kb;
      gload_lds16(gA, As + c * 4096 + wave * 1024);
      gload_lds16(gB, Bs + c * 4096 + wave * 1024);
    }
    __syncthreads();
#pragma unroll
    for (int kk = 0; kk < 2; ++kk) {
      bf16x8 a[4], b[4];
#pragma unroll
      for (int m = 0; m < 4; ++m) {
        int r = wr * 64 + m * 16 + lrow;
        a[m] = *reinterpret_cast<const bf16x8*>(
            As + r * 128 + ((kk * 64 + lk * 16) ^ ((r & 7) << 4)));
      }
#pragma unroll
      for (int n = 0; n < 4; ++n) {
        int r = wc * 64 + n * 16 + lrow;
        b[n] = *reinterpret_cast<const bf16x8*>(
            Bs + r * 128 + ((kk * 64 + lk * 16) ^ ((r & 7) << 4)));
      }
#pragma unroll
      for (int m = 0; m < 4; ++m)
#pragma unroll
        for (int n = 0; n < 4; ++n)
          acc[m][n] = __builtin_amdgcn_mfma_f32_16x16x32_bf16(a[m], b[n], acc[m][n], 0, 0, 0);
    }
  }

#pragma unroll
  for (int m = 0; m < 4; ++m) {
    int row = row0 + wr * 64 + m * 16 + lk * 4;
#pragma unroll
    for (int n = 0; n < 4; ++n) {
      int col = col0 + wc * 64 + n * 16 + lrow;
      float bv = bias[col];
#pragma unroll
      for (int j = 0; j < 4; ++j)
        C[(size_t)(row + j) * Ncols + col] = acc[m][n][j] + bv;
    }
  }
}

// ---------------------------------------------------------------- QKV GEMM with fused RMS-norm epilogue
__global__ __launch_bounds__(256, 2) void gemm_qkv_kernel(
    const unsigned short* __restrict__ A, const unsigned short* __restrict__ B,
    const float* __restrict__ bias, const float* __restrict__ qg,
    const float* __restrict__ kg, unsigned short* __restrict__ Qn,
    unsigned short* __restrict__ Kn, unsigned short* __restrict__ Vt) {
  __shared__ alignas(16) char As[128 * 128];
  __shared__ alignas(16) char Bs[128 * 128];
  const int t = threadIdx.x;
  const int lane = t & 63, wave = t >> 6;
  const int wr = wave >> 1, wc = wave & 1;
  const int lrow = lane & 15, lk = lane >> 4;
  const int row0 = blockIdx.x * 128, col0 = blockIdx.y * 128;
  const int K = CDIM;
  const f32x4 fzero = {0.f, 0.f, 0.f, 0.f};

  f32x4 acc[4][4];
#pragma unroll
  for (int m = 0; m < 4; ++m)
#pragma unroll
    for (int n = 0; n < 4; ++n) acc[m][n] = fzero;

  const int p_row = (t * 16) >> 7;
  const int p_cb  = (t * 16) & 127;

  for (int kt = 0; kt < K; kt += 64) {
    __syncthreads();
#pragma unroll
    for (int c = 0; c < 4; ++c) {
      int row = c * 32 + p_row;
      int kb = p_cb ^ ((row & 7) << 4);
      const char* gA = (const char*)A + ((size_t)(row0 + row) * K + kt) * 2 + kb;
      const char* gB = (const char*)B + ((size_t)(col0 + row) * K + kt) * 2 + kb;
      gload_lds16(gA, As + c * 4096 + wave * 1024);
      gload_lds16(gB, Bs + c * 4096 + wave * 1024);
    }
    __syncthreads();
#pragma unroll
    for (int kk = 0; kk < 2; ++kk) {
      bf16x8 a[4], b[4];
#pragma unroll
      for (int m = 0; m < 4; ++m) {
        int r = wr * 64 + m * 16 + lrow;
        a[m] = *reinterpret_cast<const bf16x8*>(
            As + r * 128 + ((kk * 64 + lk * 16) ^ ((r & 7) << 4)));
      }
#pragma unroll
      for (int n = 0; n < 4; ++n) {
        int r = wc * 64 + n * 16 + lrow;
        b[n] = *reinterpret_cast<const bf16x8*>(
            Bs + r * 128 + ((kk * 64 + lk * 16) ^ ((r & 7) << 4)));
      }
#pragma unroll
      for (int m = 0; m < 4; ++m)
#pragma unroll
        for (int n = 0; n < 4; ++n)
          acc[m][n] = __builtin_amdgcn_mfma_f32_16x16x32_bf16(a[m], b[n], acc[m][n], 0, 0, 0);
    }
  }

  // ---- fused epilogue ----
  const int typ  = col0 >> 10;                       // 0=q 1=k 2=v (block-uniform)
  const int hloc = (((col0 & 1023) >> 6) + wc) & 15; // head for this wave
  float bv[4];
#pragma unroll
  for (int n = 0; n < 4; ++n) bv[n] = bias[col0 + wc * 64 + n * 16 + lrow];

  if (typ == 2) {
#pragma unroll
    for (int m = 0; m < 4; ++m)
#pragma unroll
      for (int j = 0; j < 4; ++j) {
        int row = row0 + wr * 64 + m * 16 + lk * 4 + j;
        int np = (row & ~12) | ((row & 4) << 1) | ((row & 8) >> 1);
#pragma unroll
        for (int n = 0; n < 4; ++n) {
          int d = n * 16 + lrow;
          Vt[(size_t)(hloc * HD + d) * N_TOK + np] = f2bf(acc[m][n][j] + bv[n]);
        }
      }
  } else {
    const float* g = (typ == 0) ? qg : kg;
    const float gscale = (typ == 0) ? 1.0f : KSCALE;
    unsigned short* dst = (typ == 0) ? Qn : Kn;
    float gv[4];
#pragma unroll
    for (int n = 0; n < 4; ++n)
      gv[n] = g[hloc * HD + n * 16 + lrow] * gscale;
#pragma unroll
    for (int m = 0; m < 4; ++m)
#pragma unroll
      for (int j = 0; j < 4; ++j) {
        float tv[4];
        float ss = 0.f;
#pragma unroll
        for (int n = 0; n < 4; ++n) {
          tv[n] = acc[m][n][j] + bv[n];
          ss += tv[n] * tv[n];
        }
        ss += __shfl_xor(ss, 1);
        ss += __shfl_xor(ss, 2);
        ss += __shfl_xor(ss, 4);
        ss += __shfl_xor(ss, 8);
        float r = rsqrtf(fmaxf(ss, 1e-24f));
        int row = row0 + wr * 64 + m * 16 + lk * 4 + j;
#pragma unroll
        for (int n = 0; n < 4; ++n)
          dst[((size_t)hloc * N_TOK + row) * HD + n * 16 + lrow] =
              f2bf(tv[n] * r * gv[n]);
      }
  }
}

// ---------------------------------------------------------------- flash attention v8
// split-KV, T14 reg-staging. Both 32-key score halves computed up-front
// (8 back-to-back QK MFMAs) so exp/pack of half 0 runs on VALU while the
// matrix pipe retires QK1, and PV0 overlaps exp1: deterministic
// within-wave MFMA||VALU overlap. Packed f32x2 denominator accumulator.
__global__ __launch_bounds__(256, 4) void flash_kernel(
    const unsigned short* __restrict__ Qn, const unsigned short* __restrict__ Kn,
    const unsigned short* __restrict__ Vt, float* __restrict__ Op,
    float* __restrict__ Lp) {
  __shared__ alignas(16) char Ks[2][64 * 128];
  __shared__ alignas(16) char Vs[2][64 * 128];
  const int t = threadIdx.x, lane = t & 63, wave = t >> 6;
  const int q = lane & 31, hi = lane >> 5;
  const int h = blockIdx.y;
  const int half = blockIdx.z;
  const int q0 = blockIdx.x * 128 + wave * 32;
  const int kv0 = half << 11;

  bf16x8 bq[4];
#pragma unroll
  for (int c = 0; c < 4; ++c)
    bq[c] = *reinterpret_cast<const bf16x8*>(
        Qn + ((size_t)h * N_TOK + q0 + q) * HD + c * 16 + hi * 8);

  f32x16 ot0, ot1;
#pragma unroll
  for (int r = 0; r < 16; ++r) { ot0[r] = 0.f; ot1[r] = 0.f; }
  f32x2 l2 = {0.f, 0.f};

  // loop-invariant swizzled LDS read offsets (lane constants)
  int koff[4], voff[4];
#pragma unroll
  for (int c = 0; c < 4; ++c)
    koff[c] = q * 128 + ((c * 32 + hi * 16) ^ ((q & 7) << 4));
#pragma unroll
  for (int kt = 0; kt < 4; ++kt)
    voff[kt] = q * 128 + ((kt * 32 + hi * 16) ^ ((q & 7) << 4));

  // persistent staging pointers (pre-swizzled source), advanced per tile
  const int p_row = (t * 16) >> 7;
  const int p_cb  = (t * 16) & 127;
  const int scb   = p_cb ^ ((p_row & 7) << 4);
  const char* gK0 = (const char*)Kn + ((size_t)h * N_TOK + kv0 + p_row) * 128 + scb;
  const char* gK1 = gK0 + 32 * 128;
  const char* gV0 = (const char*)Vt + ((size_t)(h * HD + p_row) * N_TOK + kv0) * 2 + scb;
  const char* gV1 = gV0 + (size_t)32 * N_TOK * 2;

  u32x4 rK0, rK1, rV0, rV1;
  auto load_regs = [&]() {
    rK0 = *reinterpret_cast<const u32x4*>(gK0);
    rK1 = *reinterpret_cast<const u32x4*>(gK1);
    rV0 = *reinterpret_cast<const u32x4*>(gV0);
    rV1 = *reinterpret_cast<const u32x4*>(gV1);
    gK0 += 8192; gK1 += 8192; gV0 += 128; gV1 += 128;
  };
  auto write_lds = [&](int b) {
    *reinterpret_cast<u32x4*>(Ks[b] + t * 16)        = rK0;
    *reinterpret_cast<u32x4*>(Ks[b] + 4096 + t * 16) = rK1;
    *reinterpret_cast<u32x4*>(Vs[b] + t * 16)        = rV0;
    *reinterpret_cast<u32x4*>(Vs[b] + 4096 + t * 16) = rV1;
  };

  load_regs();
  write_lds(0);
  __syncthreads();
  int buf = 0;

  for (int kv = kv0; kv < kv0 + 2048; kv += 64) {
    const bool more = (kv + 64 < kv0 + 2048);
    if (more) load_regs();                 // issue next tile's loads NOW

    const char* Kb = Ks[buf];
    const char* Vb = Vs[buf];

    // QK^T for BOTH 32-key halves, issued back-to-back
    f32x16 s0, s1;
#pragma unroll
    for (int r = 0; r < 16; ++r) { s0[r] = 0.f; s1[r] = 0.f; }
    __builtin_amdgcn_s_setprio(1);
#pragma unroll
    for (int c = 0; c < 4; ++c) {
      bf16x8 kf = *reinterpret_cast<const bf16x8*>(Kb + koff[c]);
      s0 = __builtin_amdgcn_mfma_f32_32x32x16_bf16(kf, bq[c], s0, 0, 0, 0);
    }
#pragma unroll
    for (int c = 0; c < 4; ++c) {
      bf16x8 kf = *reinterpret_cast<const bf16x8*>(Kb + koff[c] + 4096);
      s1 = __builtin_amdgcn_mfma_f32_32x32x16_bf16(kf, bq[c], s1, 0, 0, 0);
    }
    __builtin_amdgcn_s_setprio(0);

    // exp/pack half 0 (depends only on s0; QK1 still in the matrix pipe)
    unsigned int W0[8];
#pragma unroll
    for (int i = 0; i < 8; ++i) {
      float p0 = fexp2(s0[2 * i]);
      float p1 = fexp2(s0[2 * i + 1]);
      W0[i] = cvt_pk_bf16(p0, p1);
      l2 += (f32x2){p0, p1};
    }

    // PV half 0 (overlaps exp/pack half 1 below)
    __builtin_amdgcn_s_setprio(1);
#pragma unroll
    for (int ktl = 0; ktl < 2; ++ktl) {
      u32x4 pw;
#pragma unroll
      for (int i = 0; i < 4; ++i) pw[i] = W0[ktl * 4 + i];
      bf16x8 pfrag = __builtin_bit_cast(bf16x8, pw);
      bf16x8 vf0 = *reinterpret_cast<const bf16x8*>(Vb + voff[ktl]);
      ot0 = __builtin_amdgcn_mfma_f32_32x32x16_bf16(vf0, pfrag, ot0, 0, 0, 0);
      bf16x8 vf1 = *reinterpret_cast<const bf16x8*>(Vb + voff[ktl] + 4096);
      ot1 = __builtin_amdgcn_mfma_f32_32x32x16_bf16(vf1, pfrag, ot1, 0, 0, 0);
    }
    __builtin_amdgcn_s_setprio(0);

    // exp/pack half 1
    unsigned int W1[8];
#pragma unroll
    for (int i = 0; i < 8; ++i) {
      float p0 = fexp2(s1[2 * i]);
      float p1 = fexp2(s1[2 * i + 1]);
      W1[i] = cvt_pk_bf16(p0, p1);
      l2 += (f32x2){p0, p1};
    }

    // PV half 1
    __builtin_amdgcn_s_setprio(1);
#pragma unroll
    for (int ktl = 0; ktl < 2; ++ktl) {
      u32x4 pw;
#pragma unroll
      for (int i = 0; i < 4; ++i) pw[i] = W1[ktl * 4 + i];
      bf16x8 pfrag = __builtin_bit_cast(bf16x8, pw);
      bf16x8 vf0 = *reinterpret_cast<const bf16x8*>(Vb + voff[2 + ktl]);
      ot0 = __builtin_amdgcn_mfma_f32_32x32x16_bf16(vf0, pfrag, ot0, 0, 0, 0);
      bf16x8 vf1 = *reinterpret_cast<const bf16x8*>(Vb + voff[2 + ktl] + 4096);
      ot1 = __builtin_amdgcn_mfma_f32_32x32x16_bf16(vf1, pfrag, ot1, 0, 0, 0);
    }
    __builtin_amdgcn_s_setprio(0);

    if (more) {
      write_lds(buf ^ 1);                  // vmcnt waited only here
      __syncthreads();
      buf ^= 1;
    }
  }

  // un-normalized partial out (fp32) + denominator partial
  float* ob = Op + ((size_t)half * N_TOK + q0 + q) * CDIM + h * HD;
#pragma unroll
  for (int g = 0; g < 4; ++g) {
    float4 v0 = {ot0[4 * g + 0], ot0[4 * g + 1], ot0[4 * g + 2], ot0[4 * g + 3]};
    float4 v1 = {ot1[4 * g + 0], ot1[4 * g + 1], ot1[4 * g + 2], ot1[4 * g + 3]};
    *reinterpret_cast<float4*>(ob + g * 8 + hi * 4) = v0;
    *reinterpret_cast<float4*>(ob + 32 + g * 8 + hi * 4) = v1;
  }
  float l = l2[0] + l2[1];
  l += __shfl_xor(l, 32);
  if (hi == 0)
    Lp[((size_t)half * NH + h) * N_TOK + q0 + q] = l;
}

// ---------------------------------------------------------------- combine halves -> bf16 Hb
__global__ __launch_bounds__(256) void combine_kernel(
    const float* __restrict__ Op, const float* __restrict__ Lp,
    unsigned short* __restrict__ Hb) {
  int i = blockIdx.x * 256 + threadIdx.x;          // float4 index, N*C/4 total
  int c = (i & (CDIM / 4 - 1)) * 4;
  int n = i >> 8;
  int h = c >> 6;
  float l0 = Lp[(size_t)h * N_TOK + n];
  float l1 = Lp[((size_t)NH + h) * N_TOK + n];
  float rl = 1.0f / (l0 + l1);
  float4 a = reinterpret_cast<const float4*>(Op)[i];
  float4 b = reinterpret_cast<const float4*>(Op + (size_t)N_TOK * CDIM)[i];
  ushort4 u;
  u.x = f2bf((a.x + b.x) * rl);
  u.y = f2bf((a.y + b.y) * rl);
  u.z = f2bf((a.z + b.z) * rl);
  u.w = f2bf((a.w + b.w) * rl);
  reinterpret_cast<ushort4*>(Hb)[i] = u;
}

// ---------------------------------------------------------------- launch
extern "C" void kernel_launch(void* const* d_in, const int* in_sizes, int n_in,
                              void* d_out, int out_size, void* d_ws, size_t ws_size,
                              hipStream_t stream) {
  const float* x    = (const float*)d_in[0];
  const float* Wqkv = (const float*)d_in[1];
  const float* bqkv = (const float*)d_in[2];
  const float* qg   = (const float*)d_in[3];
  const float* kg   = (const float*)d_in[4];
  const float* Wout = (const float*)d_in[5];
  const float* bout = (const float*)d_in[6];
  float* out = (float*)d_out;

  char* ws = (char*)d_ws;
  unsigned short* xb  = (unsigned short*)(ws);
  unsigned short* w1b = (unsigned short*)(ws + ((size_t)8  << 20));
  unsigned short* w2b = (unsigned short*)(ws + ((size_t)14 << 20));
  float*          Op  = (float*)         (ws + ((size_t)16 << 20));  // 32MB
  float*          Lp  = (float*)         (ws + ((size_t)48 << 20));  // 0.5MB
  unsigned short* Qn  = (unsigned short*)(ws + ((size_t)64 << 20));
  unsigned short* Kn  = (unsigned short*)(ws + ((size_t)72 << 20));
  unsigned short* Vt  = (unsigned short*)(ws + ((size_t)80 << 20));
  unsigned short* Hb  = (unsigned short*)(ws + ((size_t)88 << 20));

  pack_bf16_kernel<<<8192, 256, 0, stream>>>(x, Wqkv, Wout, xb, w1b, w2b);
  gemm_qkv_kernel<<<dim3(32, 24), 256, 0, stream>>>(xb, w1b, bqkv, qg, kg,
                                                    Qn, Kn, Vt);
  flash_kernel<<<dim3(32, 16, 2), 256, 0, stream>>>(Qn, Kn, Vt, Op, Lp);
  combine_kernel<<<4096, 256, 0, stream>>>(Op, Lp, Hb);
  gemm_bt_kernel<<<dim3(32, 8), 256, 0, stream>>>(Hb, w2b, bout, out,
                                                  N_TOK, CDIM, CDIM);
}

// Round 10
// 140.839 us; speedup vs baseline: 1.4973x; 1.0232x over previous
//
#include <hip/hip_runtime.h>
#include <math.h>

#define N_TOK 4096
#define CDIM  1024
#define NH    16
#define HD    64

// scores: |q̂γ · k̂γ√D| <= 8 (γ=1), folded to log2 domain via K scale.
#define KSCALE 11.5416469f   // 8 * log2(e)

typedef __attribute__((ext_vector_type(8)))  __bf16 bf16x8;
typedef __attribute__((ext_vector_type(2)))  float  f32x2;
typedef __attribute__((ext_vector_type(4)))  float  f32x4;
typedef __attribute__((ext_vector_type(16))) float  f32x16;
typedef __attribute__((ext_vector_type(4)))  unsigned int u32x4;

__device__ __forceinline__ unsigned short f2bf(float f) {
  unsigned int u = __builtin_bit_cast(unsigned int, f);
  u += 0x7FFFu + ((u >> 16) & 1u);            // RTNE
  return (unsigned short)(u >> 16);
}

__device__ __forceinline__ unsigned int cvt_pk_bf16(float lo, float hi) {
  unsigned int w;
  asm("v_cvt_pk_bf16_f32 %0, %1, %2" : "=v"(w) : "v"(lo), "v"(hi));
  return w;
}

// bare v_exp_f32 — inputs are in [-12, 12], no denormal handling needed
__device__ __forceinline__ float fexp2(float x) {
#if __has_builtin(__builtin_amdgcn_exp2f)
  return __builtin_amdgcn_exp2f(x);
#else
  return exp2f(x);
#endif
}

__device__ __forceinline__ void gload_lds16(const void* g, void* lds) {
  __builtin_amdgcn_global_load_lds(
      (const __attribute__((address_space(1))) unsigned int*)g,
      (__attribute__((address_space(3))) unsigned int*)lds, 16, 0, 0);
}

// ---------------------------------------------------------------- pack fp32->bf16
__global__ __launch_bounds__(256) void pack_bf16_kernel(
    const float* __restrict__ x, const float* __restrict__ w1,
    const float* __restrict__ w2, unsigned short* __restrict__ xb,
    unsigned short* __restrict__ w1b, unsigned short* __restrict__ w2b) {
  const size_t X4 = (size_t)N_TOK * CDIM / 4;
  const size_t W14 = (size_t)3 * CDIM * CDIM / 4;
  const size_t W24 = (size_t)CDIM * CDIM / 4;
  size_t i = (size_t)blockIdx.x * blockDim.x + threadIdx.x;
  const float* src; unsigned short* dst; size_t off;
  if (i < X4)              { src = x;  dst = xb;  off = i; }
  else if (i < X4 + W14)   { src = w1; dst = w1b; off = i - X4; }
  else if (i < X4 + W14 + W24) { src = w2; dst = w2b; off = i - X4 - W14; }
  else return;
  float4 v = reinterpret_cast<const float4*>(src)[off];
  ushort4 u;
  u.x = f2bf(v.x); u.y = f2bf(v.y); u.z = f2bf(v.z); u.w = f2bf(v.w);
  reinterpret_cast<ushort4*>(dst)[off] = u;
}

// ---------------------------------------------------------------- bf16 GEMM, C = A * B^T + bias (fp32 out)
__global__ __launch_bounds__(256, 2) void gemm_bt_kernel(
    const unsigned short* __restrict__ A, const unsigned short* __restrict__ B,
    const float* __restrict__ bias, float* __restrict__ C,
    int M, int Ncols, int K) {
  __shared__ alignas(16) char As[128 * 128];
  __shared__ alignas(16) char Bs[128 * 128];
  const int t = threadIdx.x;
  const int lane = t & 63, wave = t >> 6;
  const int wr = wave >> 1, wc = wave & 1;
  const int lrow = lane & 15, lk = lane >> 4;
  const int row0 = blockIdx.x * 128, col0 = blockIdx.y * 128;
  const f32x4 fzero = {0.f, 0.f, 0.f, 0.f};

  f32x4 acc[4][4];
#pragma unroll
  for (int m = 0; m < 4; ++m)
#pragma unroll
    for (int n = 0; n < 4; ++n) acc[m][n] = fzero;

  const int p_row = (t * 16) >> 7;
  const int p_cb  = (t * 16) & 127;

  for (int kt = 0; kt < K; kt += 64) {
    __syncthreads();
#pragma unroll
    for (int c = 0; c < 4; ++c) {
      int row = c * 32 + p_row;
      int kb = p_cb ^ ((row & 7) << 4);
      const char* gA = (const char*)A + ((size_t)(row0 + row) * K + kt) * 2 + kb;
      const char* gB = (const char*)B + ((size_t)(col0 + row) * K + kt) * 2 + kb;
      gload_lds16(gA, As + c * 4096 + wave * 1024);
      gload_lds16(gB, Bs + c * 4096 + wave * 1024);
    }
    __syncthreads();
#pragma unroll
    for (int kk = 0; kk < 2; ++kk) {
      bf16x8 a[4], b[4];
#pragma unroll
      for (int m = 0; m < 4; ++m) {
        int r = wr * 64 + m * 16 + lrow;
        a[m] = *reinterpret_cast<const bf16x8*>(
            As + r * 128 + ((kk * 64 + lk * 16) ^ ((r & 7) << 4)));
      }
#pragma unroll
      for (int n = 0; n < 4; ++n) {
        int r = wc * 64 + n * 16 + lrow;
        b[n] = *reinterpret_cast<const bf16x8*>(
            Bs + r * 128 + ((kk * 64 + lk * 16) ^ ((r & 7) << 4)));
      }
#pragma unroll
      for (int m = 0; m < 4; ++m)
#pragma unroll
        for (int n = 0; n < 4; ++n)
          acc[m][n] = __builtin_amdgcn_mfma_f32_16x16x32_bf16(a[m], b[n], acc[m][n], 0, 0, 0);
    }
  }

#pragma unroll
  for (int m = 0; m < 4; ++m) {
    int row = row0 + wr * 64 + m * 16 + lk * 4;
#pragma unroll
    for (int n = 0; n < 4; ++n) {
      int col = col0 + wc * 64 + n * 16 + lrow;
      float bv = bias[col];
#pragma unroll
      for (int j = 0; j < 4; ++j)
        C[(size_t)(row + j) * Ncols + col] = acc[m][n][j] + bv;
    }
  }
}

// ---------------------------------------------------------------- QKV GEMM with fused RMS-norm epilogue
__global__ __launch_bounds__(256, 2) void gemm_qkv_kernel(
    const unsigned short* __restrict__ A, const unsigned short* __restrict__ B,
    const float* __restrict__ bias, const float* __restrict__ qg,
    const float* __restrict__ kg, unsigned short* __restrict__ Qn,
    unsigned short* __restrict__ Kn, unsigned short* __restrict__ Vt) {
  __shared__ alignas(16) char As[128 * 128];
  __shared__ alignas(16) char Bs[128 * 128];
  const int t = threadIdx.x;
  const int lane = t & 63, wave = t >> 6;
  const int wr = wave >> 1, wc = wave & 1;
  const int lrow = lane & 15, lk = lane >> 4;
  const int row0 = blockIdx.x * 128, col0 = blockIdx.y * 128;
  const int K = CDIM;
  const f32x4 fzero = {0.f, 0.f, 0.f, 0.f};

  f32x4 acc[4][4];
#pragma unroll
  for (int m = 0; m < 4; ++m)
#pragma unroll
    for (int n = 0; n < 4; ++n) acc[m][n] = fzero;

  const int p_row = (t * 16) >> 7;
  const int p_cb  = (t * 16) & 127;

  for (int kt = 0; kt < K; kt += 64) {
    __syncthreads();
#pragma unroll
    for (int c = 0; c < 4; ++c) {
      int row = c * 32 + p_row;
      int kb = p_cb ^ ((row & 7) << 4);
      const char* gA = (const char*)A + ((size_t)(row0 + row) * K + kt) * 2 + kb;
      const char* gB = (const char*)B + ((size_t)(col0 + row) * K + kt) * 2 + kb;
      gload_lds16(gA, As + c * 4096 + wave * 1024);
      gload_lds16(gB, Bs + c * 4096 + wave * 1024);
    }
    __syncthreads();
#pragma unroll
    for (int kk = 0; kk < 2; ++kk) {
      bf16x8 a[4], b[4];
#pragma unroll
      for (int m = 0; m < 4; ++m) {
        int r = wr * 64 + m * 16 + lrow;
        a[m] = *reinterpret_cast<const bf16x8*>(
            As + r * 128 + ((kk * 64 + lk * 16) ^ ((r & 7) << 4)));
      }
#pragma unroll
      for (int n = 0; n < 4; ++n) {
        int r = wc * 64 + n * 16 + lrow;
        b[n] = *reinterpret_cast<const bf16x8*>(
            Bs + r * 128 + ((kk * 64 + lk * 16) ^ ((r & 7) << 4)));
      }
#pragma unroll
      for (int m = 0; m < 4; ++m)
#pragma unroll
        for (int n = 0; n < 4; ++n)
          acc[m][n] = __builtin_amdgcn_mfma_f32_16x16x32_bf16(a[m], b[n], acc[m][n], 0, 0, 0);
    }
  }

  // ---- fused epilogue ----
  const int typ  = col0 >> 10;                       // 0=q 1=k 2=v (block-uniform)
  const int hloc = (((col0 & 1023) >> 6) + wc) & 15; // head for this wave
  float bv[4];
#pragma unroll
  for (int n = 0; n < 4; ++n) bv[n] = bias[col0 + wc * 64 + n * 16 + lrow];

  if (typ == 2) {
#pragma unroll
    for (int m = 0; m < 4; ++m)
#pragma unroll
      for (int j = 0; j < 4; ++j) {
        int row = row0 + wr * 64 + m * 16 + lk * 4 + j;
        int np = (row & ~12) | ((row & 4) << 1) | ((row & 8) >> 1);
#pragma unroll
        for (int n = 0; n < 4; ++n) {
          int d = n * 16 + lrow;
          Vt[(size_t)(hloc * HD + d) * N_TOK + np] = f2bf(acc[m][n][j] + bv[n]);
        }
      }
  } else {
    const float* g = (typ == 0) ? qg : kg;
    const float gscale = (typ == 0) ? 1.0f : KSCALE;
    unsigned short* dst = (typ == 0) ? Qn : Kn;
    float gv[4];
#pragma unroll
    for (int n = 0; n < 4; ++n)
      gv[n] = g[hloc * HD + n * 16 + lrow] * gscale;
#pragma unroll
    for (int m = 0; m < 4; ++m)
#pragma unroll
      for (int j = 0; j < 4; ++j) {
        float tv[4];
        float ss = 0.f;
#pragma unroll
        for (int n = 0; n < 4; ++n) {
          tv[n] = acc[m][n][j] + bv[n];
          ss += tv[n] * tv[n];
        }
        ss += __shfl_xor(ss, 1);
        ss += __shfl_xor(ss, 2);
        ss += __shfl_xor(ss, 4);
        ss += __shfl_xor(ss, 8);
        float r = rsqrtf(fmaxf(ss, 1e-24f));
        int row = row0 + wr * 64 + m * 16 + lk * 4 + j;
#pragma unroll
        for (int n = 0; n < 4; ++n)
          dst[((size_t)hloc * N_TOK + row) * HD + n * 16 + lrow] =
              f2bf(tv[n] * r * gv[n]);
      }
  }
}

// ---------------------------------------------------------------- flash attention v9
// split-KV, T14 reg-staging. 64 q-rows per wave (2 q-sub-tiles A,B):
// every K/V ds_read_b128 feeds TWO MFMAs -> LDS-pipe traffic per MFMA
// halves (was the most-loaded pipe at ~67%). QK chains for A/B naturally
// interleave on the shared kf. 2 waves/SIMD (reg-heavy, deliberate).
__global__ __launch_bounds__(256, 2) void flash_kernel(
    const unsigned short* __restrict__ Qn, const unsigned short* __restrict__ Kn,
    const unsigned short* __restrict__ Vt, float* __restrict__ Op,
    float* __restrict__ Lp) {
  __shared__ alignas(16) char Ks[2][64 * 128];
  __shared__ alignas(16) char Vs[2][64 * 128];
  const int t = threadIdx.x, lane = t & 63, wave = t >> 6;
  const int q = lane & 31, hi = lane >> 5;
  const int h = blockIdx.y;
  const int half = blockIdx.z;
  const int q0 = blockIdx.x * 256 + wave * 64;     // wave owns q0..q0+63
  const int kv0 = half << 11;

  bf16x8 bqA[4], bqB[4];
#pragma unroll
  for (int c = 0; c < 4; ++c) {
    bqA[c] = *reinterpret_cast<const bf16x8*>(
        Qn + ((size_t)h * N_TOK + q0 + q) * HD + c * 16 + hi * 8);
    bqB[c] = *reinterpret_cast<const bf16x8*>(
        Qn + ((size_t)h * N_TOK + q0 + 32 + q) * HD + c * 16 + hi * 8);
  }

  f32x16 otA0, otA1, otB0, otB1;
#pragma unroll
  for (int r = 0; r < 16; ++r) {
    otA0[r] = 0.f; otA1[r] = 0.f; otB0[r] = 0.f; otB1[r] = 0.f;
  }
  f32x2 l2A = {0.f, 0.f}, l2B = {0.f, 0.f};

  // loop-invariant swizzled LDS read offsets (lane constants)
  int koff[4], voff[4];
#pragma unroll
  for (int c = 0; c < 4; ++c)
    koff[c] = q * 128 + ((c * 32 + hi * 16) ^ ((q & 7) << 4));
#pragma unroll
  for (int kt = 0; kt < 4; ++kt)
    voff[kt] = q * 128 + ((kt * 32 + hi * 16) ^ ((q & 7) << 4));

  // persistent staging pointers (pre-swizzled source), advanced per tile
  const int p_row = (t * 16) >> 7;
  const int p_cb  = (t * 16) & 127;
  const int scb   = p_cb ^ ((p_row & 7) << 4);
  const char* gK0 = (const char*)Kn + ((size_t)h * N_TOK + kv0 + p_row) * 128 + scb;
  const char* gK1 = gK0 + 32 * 128;
  const char* gV0 = (const char*)Vt + ((size_t)(h * HD + p_row) * N_TOK + kv0) * 2 + scb;
  const char* gV1 = gV0 + (size_t)32 * N_TOK * 2;

  u32x4 rK0, rK1, rV0, rV1;
  auto load_regs = [&]() {
    rK0 = *reinterpret_cast<const u32x4*>(gK0);
    rK1 = *reinterpret_cast<const u32x4*>(gK1);
    rV0 = *reinterpret_cast<const u32x4*>(gV0);
    rV1 = *reinterpret_cast<const u32x4*>(gV1);
    gK0 += 8192; gK1 += 8192; gV0 += 128; gV1 += 128;
  };
  auto write_lds = [&](int b) {
    *reinterpret_cast<u32x4*>(Ks[b] + t * 16)        = rK0;
    *reinterpret_cast<u32x4*>(Ks[b] + 4096 + t * 16) = rK1;
    *reinterpret_cast<u32x4*>(Vs[b] + t * 16)        = rV0;
    *reinterpret_cast<u32x4*>(Vs[b] + 4096 + t * 16) = rV1;
  };

  load_regs();
  write_lds(0);
  __syncthreads();
  int buf = 0;

  for (int kv = kv0; kv < kv0 + 2048; kv += 64) {
    const bool more = (kv + 64 < kv0 + 2048);
    if (more) load_regs();                 // issue next tile's loads NOW

    const char* Kb = Ks[buf];
    const char* Vb = Vs[buf];

#pragma unroll
    for (int hblk = 0; hblk < 2; ++hblk) {      // keys hblk*32 .. hblk*32+31
      // QK^T for both q-subs; each kf read feeds two MFMAs
      f32x16 sA, sB;
#pragma unroll
      for (int r = 0; r < 16; ++r) { sA[r] = 0.f; sB[r] = 0.f; }
      __builtin_amdgcn_s_setprio(1);
#pragma unroll
      for (int c = 0; c < 4; ++c) {
        bf16x8 kf = *reinterpret_cast<const bf16x8*>(Kb + koff[c] + hblk * 4096);
        sA = __builtin_amdgcn_mfma_f32_32x32x16_bf16(kf, bqA[c], sA, 0, 0, 0);
        sB = __builtin_amdgcn_mfma_f32_32x32x16_bf16(kf, bqB[c], sB, 0, 0, 0);
      }
      __builtin_amdgcn_s_setprio(0);

      // exp/pack both q-subs
      unsigned int WA[8], WB[8];
#pragma unroll
      for (int i = 0; i < 8; ++i) {
        float a0 = fexp2(sA[2 * i]);
        float a1 = fexp2(sA[2 * i + 1]);
        WA[i] = cvt_pk_bf16(a0, a1);
        l2A += (f32x2){a0, a1};
        float b0 = fexp2(sB[2 * i]);
        float b1 = fexp2(sB[2 * i + 1]);
        WB[i] = cvt_pk_bf16(b0, b1);
        l2B += (f32x2){b0, b1};
      }

      // PV: each vf read feeds two MFMAs
      __builtin_amdgcn_s_setprio(1);
#pragma unroll
      for (int ktl = 0; ktl < 2; ++ktl) {
        const int kt = hblk * 2 + ktl;
        u32x4 pwA, pwB;
#pragma unroll
        for (int i = 0; i < 4; ++i) { pwA[i] = WA[ktl * 4 + i]; pwB[i] = WB[ktl * 4 + i]; }
        bf16x8 pfA = __builtin_bit_cast(bf16x8, pwA);
        bf16x8 pfB = __builtin_bit_cast(bf16x8, pwB);
        bf16x8 vf0 = *reinterpret_cast<const bf16x8*>(Vb + voff[kt]);
        otA0 = __builtin_amdgcn_mfma_f32_32x32x16_bf16(vf0, pfA, otA0, 0, 0, 0);
        otB0 = __builtin_amdgcn_mfma_f32_32x32x16_bf16(vf0, pfB, otB0, 0, 0, 0);
        bf16x8 vf1 = *reinterpret_cast<const bf16x8*>(Vb + voff[kt] + 4096);
        otA1 = __builtin_amdgcn_mfma_f32_32x32x16_bf16(vf1, pfA, otA1, 0, 0, 0);
        otB1 = __builtin_amdgcn_mfma_f32_32x32x16_bf16(vf1, pfB, otB1, 0, 0, 0);
      }
      __builtin_amdgcn_s_setprio(0);
    }

    if (more) {
      write_lds(buf ^ 1);                  // vmcnt waited only here
      __syncthreads();
      buf ^= 1;
    }
  }

  // un-normalized partial out (fp32) + denominator partials
  float* obA = Op + ((size_t)half * N_TOK + q0 + q) * CDIM + h * HD;
  float* obB = Op + ((size_t)half * N_TOK + q0 + 32 + q) * CDIM + h * HD;
#pragma unroll
  for (int g = 0; g < 4; ++g) {
    float4 vA0 = {otA0[4 * g + 0], otA0[4 * g + 1], otA0[4 * g + 2], otA0[4 * g + 3]};
    float4 vA1 = {otA1[4 * g + 0], otA1[4 * g + 1], otA1[4 * g + 2], otA1[4 * g + 3]};
    *reinterpret_cast<float4*>(obA + g * 8 + hi * 4) = vA0;
    *reinterpret_cast<float4*>(obA + 32 + g * 8 + hi * 4) = vA1;
    float4 vB0 = {otB0[4 * g + 0], otB0[4 * g + 1], otB0[4 * g + 2], otB0[4 * g + 3]};
    float4 vB1 = {otB1[4 * g + 0], otB1[4 * g + 1], otB1[4 * g + 2], otB1[4 * g + 3]};
    *reinterpret_cast<float4*>(obB + g * 8 + hi * 4) = vB0;
    *reinterpret_cast<float4*>(obB + 32 + g * 8 + hi * 4) = vB1;
  }
  float lA = l2A[0] + l2A[1];
  float lB = l2B[0] + l2B[1];
  lA += __shfl_xor(lA, 32);
  lB += __shfl_xor(lB, 32);
  if (hi == 0) {
    Lp[((size_t)half * NH + h) * N_TOK + q0 + q] = lA;
    Lp[((size_t)half * NH + h) * N_TOK + q0 + 32 + q] = lB;
  }
}

// ---------------------------------------------------------------- combine halves -> bf16 Hb
__global__ __launch_bounds__(256) void combine_kernel(
    const float* __restrict__ Op, const float* __restrict__ Lp,
    unsigned short* __restrict__ Hb) {
  int i = blockIdx.x * 256 + threadIdx.x;          // float4 index, N*C/4 total
  int c = (i & (CDIM / 4 - 1)) * 4;
  int n = i >> 8;
  int h = c >> 6;
  float l0 = Lp[(size_t)h * N_TOK + n];
  float l1 = Lp[((size_t)NH + h) * N_TOK + n];
  float rl = 1.0f / (l0 + l1);
  float4 a = reinterpret_cast<const float4*>(Op)[i];
  float4 b = reinterpret_cast<const float4*>(Op + (size_t)N_TOK * CDIM)[i];
  ushort4 u;
  u.x = f2bf((a.x + b.x) * rl);
  u.y = f2bf((a.y + b.y) * rl);
  u.z = f2bf((a.z + b.z) * rl);
  u.w = f2bf((a.w + b.w) * rl);
  reinterpret_cast<ushort4*>(Hb)[i] = u;
}

// ---------------------------------------------------------------- launch
extern "C" void kernel_launch(void* const* d_in, const int* in_sizes, int n_in,
                              void* d_out, int out_size, void* d_ws, size_t ws_size,
                              hipStream_t stream) {
  const float* x    = (const float*)d_in[0];
  const float* Wqkv = (const float*)d_in[1];
  const float* bqkv = (const float*)d_in[2];
  const float* qg   = (const float*)d_in[3];
  const float* kg   = (const float*)d_in[4];
  const float* Wout = (const float*)d_in[5];
  const float* bout = (const float*)d_in[6];
  float* out = (float*)d_out;

  char* ws = (char*)d_ws;
  unsigned short* xb  = (unsigned short*)(ws);
  unsigned short* w1b = (unsigned short*)(ws + ((size_t)8  << 20));
  unsigned short* w2b = (unsigned short*)(ws + ((size_t)14 << 20));
  float*          Op  = (float*)         (ws + ((size_t)16 << 20));  // 32MB
  float*          Lp  = (float*)         (ws + ((size_t)48 << 20));  // 0.5MB
  unsigned short* Qn  = (unsigned short*)(ws + ((size_t)64 << 20));
  unsigned short* Kn  = (unsigned short*)(ws + ((size_t)72 << 20));
  unsigned short* Vt  = (unsigned short*)(ws + ((size_t)80 << 20));
  unsigned short* Hb  = (unsigned short*)(ws + ((size_t)88 << 20));

  pack_bf16_kernel<<<8192, 256, 0, stream>>>(x, Wqkv, Wout, xb, w1b, w2b);
  gemm_qkv_kernel<<<dim3(32, 24), 256, 0, stream>>>(xb, w1b, bqkv, qg, kg,
                                                    Qn, Kn, Vt);
  flash_kernel<<<dim3(16, 16, 2), 256, 0, stream>>>(Qn, Kn, Vt, Op, Lp);
  combine_kernel<<<4096, 256, 0, stream>>>(Op, Lp, Hb);
  gemm_bt_kernel<<<dim3(32, 8), 256, 0, stream>>>(Hb, w2b, bout, out,
                                                  N_TOK, CDIM, CDIM);
}